// Round 16
// baseline (280.755 us; speedup 1.0000x reference)
//
#include <hip/hip_runtime.h>
#include <hip/hip_bf16.h>

#define HH 192
#define WW 192
#define NWIN 12
#define WSZ 16
#define OWSZ 24
#define PADK 4
#define NQ1 256      // WS*WS
#define NKV1 576     // OWS*OWS
#define C2K 64
#define H2K 4
#define HD 16        // head dim
#define NTOK (HH*WW)
#define LOG2E 1.4426950408889634f
#define QSCALE (0.25f * LOG2E)

typedef __hip_bfloat16 bf16;
typedef __attribute__((ext_vector_type(8))) short bf16x8;
typedef __attribute__((ext_vector_type(4))) float f32x4;

union B8 { short s[8]; bf16x8 v; unsigned u[4]; };

__device__ __forceinline__ unsigned cvtpk(float lo, float hi)
{
    unsigned r;
    asm("v_cvt_pk_bf16_f32 %0, %1, %2" : "=v"(r) : "v"(lo), "v"(hi));
    return r;
}
__device__ __forceinline__ float bfu2f(unsigned short u)
{
    return __uint_as_float(((unsigned)u) << 16);
}
__device__ __forceinline__ float bflo(unsigned u) { return __uint_as_float(u << 16); }
__device__ __forceinline__ float bfhi(unsigned u) { return __uint_as_float(u & 0xffff0000u); }

// ---------------- combined projection weight, transposed bf16, PERMUTED columns ----------------
// qkv row layout (cols 0..383): [q1:0-63][q2:64-127][KV1:128-255][KV2:256-383]
//   KV1 head h: cols 128+32h+(0..15)=K1[h][d], 128+32h+(16..31)=V1[h][d]  (one 64B line per head)
__global__ void wcombT_kernel(const float* __restrict__ q1_w, const float* __restrict__ kv1_w,
                              const float* __restrict__ q2_w, const float* __restrict__ kv2_w,
                              bf16* __restrict__ WT)
{
    int idx = blockIdx.x * 256 + threadIdx.x;
    if (idx >= 384 * 128) return;
    int cp = idx >> 7, r = idx & 127;
    int c;   // original semantic column
    if (cp < 64) c = cp;
    else if (cp < 128) c = 192 + (cp - 64);
    else if (cp < 256) {
        int j = cp - 128, h = j >> 5, m = j & 31;
        c = (m < 16) ? (64 + 16 * h + m) : (128 + 16 * h + (m - 16));
    } else {
        int j = cp - 256, h = j >> 5, m = j & 31;
        c = (m < 16) ? (256 + 16 * h + m) : (320 + 16 * h + (m - 16));
    }
    float v = 0.f;
    if (c < 64)       { if (r < 64)  v = q1_w[r * 64 + c] * QSCALE; }
    else if (c < 192) { if (r >= 64) v = kv1_w[(r - 64) * 128 + (c - 64)]; }
    else if (c < 256) { if (r >= 64) v = q2_w[(r - 64) * 64 + (c - 192)] * QSCALE; }
    else              { if (r < 64)  v = kv2_w[r * 128 + (c - 256)]; }
    WT[idx] = __float2bfloat16(v);
}

// ---------------- generic weight transpose to bf16: dst[n][k] = src[k][n], K=128 ----------------
__global__ void wtrans_kernel(const float* __restrict__ src, int N, bf16* __restrict__ dst)
{
    int idx = blockIdx.x * 256 + threadIdx.x;
    if (idx >= N * 128) return;
    int n = idx >> 7, k = idx & 127;
    dst[idx] = __float2bfloat16(src[(size_t)k * N + n]);
}

// ---------------- bias transposes (pre-scaled by log2(e)) ----------------
__global__ void bias1_kernel(const float* __restrict__ rpb1, const int* __restrict__ rpi,
                             float* __restrict__ biasT)   // [h][n][q]
{
    int idx = blockIdx.x * 256 + threadIdx.x;
    if (idx >= H2K * NKV1 * NQ1) return;
    int q = idx & 255;
    int n = (idx >> 8) % NKV1;
    int h = idx / (NKV1 * NQ1);
    biasT[idx] = rpb1[rpi[q * NKV1 + n] * H2K + h] * LOG2E;
}

__global__ void bias2_kernel(const float* __restrict__ rpb2, const int* __restrict__ rpi,
                             float* __restrict__ biasT)   // [h][k][q]
{
    int idx = blockIdx.x * 256 + threadIdx.x;
    if (idx >= H2K * NQ1 * NKV1) return;
    int q = idx % NKV1;
    int k = (idx / NKV1) % NQ1;
    int h = idx / (NKV1 * NQ1);
    biasT[idx] = rpb2[rpi[k * NKV1 + q] * H2K + h] * LOG2E;
}

// ---------------- qkv GEMM (N=384) with fused LN1 -> qkv bf16 (192-uint rows) + lnx f32 ----------------
__launch_bounds__(256)
__global__ void gemm_qkv(const float* __restrict__ x_tkn,
                         const float* __restrict__ ln1w, const float* __restrict__ ln1b,
                         const bf16* __restrict__ WT,
                         unsigned* __restrict__ qkvo, float* __restrict__ lnx)
{
    const int tid = threadIdx.x;
    const int lane = tid & 63, w = tid >> 6;
    const int g = lane >> 4, nl = lane & 15;

    bf16x8 wf[6][4];
#pragma unroll
    for (int t = 0; t < 6; t++) {
        const bf16* wp = WT + (size_t)((w * 6 + t) * 16 + nl) * 128;
#pragma unroll
        for (int ks = 0; ks < 4; ks++)
            wf[t][ks] = *(const bf16x8*)(wp + ks * 32 + 8 * g);
    }

    const int row = (blockIdx.x * 4 + blockIdx.y) * 16 + nl;
    const float* ap = x_tkn + (size_t)row * 128 + 8 * g;

    float av[4][8];
    float s = 0.f, sq = 0.f;
#pragma unroll
    for (int ks = 0; ks < 4; ks++) {
        float4 v0 = *(const float4*)(ap + ks * 32);
        float4 v1 = *(const float4*)(ap + ks * 32 + 4);
        av[ks][0] = v0.x; av[ks][1] = v0.y; av[ks][2] = v0.z; av[ks][3] = v0.w;
        av[ks][4] = v1.x; av[ks][5] = v1.y; av[ks][6] = v1.z; av[ks][7] = v1.w;
#pragma unroll
        for (int j = 0; j < 8; j++) { s += av[ks][j]; sq += av[ks][j] * av[ks][j]; }
    }
    s  += __shfl_xor(s, 16);  s  += __shfl_xor(s, 32);
    sq += __shfl_xor(sq, 16); sq += __shfl_xor(sq, 32);
    float mu  = s * 0.0078125f;
    float var = fmaxf(sq * 0.0078125f - mu * mu, 0.f);
    float inv = 1.0f / sqrtf(var + 1e-5f);

    bf16x8 xf[4];
#pragma unroll
    for (int ks = 0; ks < 4; ks++) {
        int col = ks * 32 + 8 * g;
        float4 g0 = *(const float4*)(ln1w + col);
        float4 g1 = *(const float4*)(ln1w + col + 4);
        float4 b0 = *(const float4*)(ln1b + col);
        float4 b1 = *(const float4*)(ln1b + col + 4);
        float nv[8];
        nv[0] = (av[ks][0] - mu) * inv * g0.x + b0.x;
        nv[1] = (av[ks][1] - mu) * inv * g0.y + b0.y;
        nv[2] = (av[ks][2] - mu) * inv * g0.z + b0.z;
        nv[3] = (av[ks][3] - mu) * inv * g0.w + b0.w;
        nv[4] = (av[ks][4] - mu) * inv * g1.x + b1.x;
        nv[5] = (av[ks][5] - mu) * inv * g1.y + b1.y;
        nv[6] = (av[ks][6] - mu) * inv * g1.z + b1.z;
        nv[7] = (av[ks][7] - mu) * inv * g1.w + b1.w;
        if (w == 0) {
            float* lp = lnx + (size_t)row * 128 + col;
            *(float4*)lp       = make_float4(nv[0], nv[1], nv[2], nv[3]);
            *(float4*)(lp + 4) = make_float4(nv[4], nv[5], nv[6], nv[7]);
        }
        B8 f;
        f.u[0] = cvtpk(nv[0], nv[1]);
        f.u[1] = cvtpk(nv[2], nv[3]);
        f.u[2] = cvtpk(nv[4], nv[5]);
        f.u[3] = cvtpk(nv[6], nv[7]);
        xf[ks] = f.v;
    }

    const f32x4 zz = {0.f, 0.f, 0.f, 0.f};
    f32x4 acc[6];
#pragma unroll
    for (int t = 0; t < 6; t++) acc[t] = zz;
#pragma unroll
    for (int ks = 0; ks < 4; ks++)
#pragma unroll
        for (int t = 0; t < 6; t++)
            acc[t] = __builtin_amdgcn_mfma_f32_16x16x32_bf16(wf[t][ks], xf[ks], acc[t], 0, 0, 0);

#pragma unroll
    for (int t = 0; t < 6; t++) {
        int n0t = (w * 6 + t) * 16 + 4 * g;
        uint2 o;
        o.x = cvtpk(acc[t][0], acc[t][1]);
        o.y = cvtpk(acc[t][2], acc[t][3]);
        *(uint2*)(qkvo + (size_t)row * 192 + (n0t >> 1)) = o;
    }
}

// ---------------- fused attention. grid (720, 4). V pre-transposed; bias as MFMA C ----------------
// qkv row (uints): [q1:0-31][q2:32-63][KV1:64-127 (head h at 64+16h: K8|V8)][KV2:128-191]
__launch_bounds__(256)
__global__ void attn_fused(const unsigned* __restrict__ qkvu,
                           const float* __restrict__ lnx,
                           const float* __restrict__ bias1T,   // [h][n][q]
                           const float* __restrict__ bias2T,   // [h][k][q]
                           float* __restrict__ xcat,
                           float* __restrict__ bb)
{
    __shared__ unsigned K_lds[NKV1][10];
    __shared__ unsigned short Vt[18][64][8];

    const int h = blockIdx.y;
    const int tid = threadIdx.x;
    const int lane = tid & 63, w = tid >> 6;
    const int g = lane >> 4, qloc = lane & 15;
    const f32x4 zz = {0.f, 0.f, 0.f, 0.f};

    if (blockIdx.x < 288) {
        // ---------------- attn1: 256 window q x 576 patch keys ----------------
        const int win = blockIdx.x % 144, z = blockIdx.x / 144;
        const int wi = win / NWIN, wj = win % NWIN;

        for (int n = tid; n < NKV1; n += 256) {
            int rr = wi * WSZ - PADK + n / OWSZ, cc = wj * WSZ - PADK + n % OWSZ;
            bool ib = (rr >= 0 && rr < HH && cc >= 0 && cc < WW);
            uint4 k0v = make_uint4(0, 0, 0, 0), k1v = k0v, v0v = k0v, v1v = k0v;
            if (ib) {
                const unsigned* src = qkvu + (size_t)(rr * WW + cc) * 192 + 64 + 16 * h;
                k0v = *(const uint4*)(src);
                k1v = *(const uint4*)(src + 4);
                v0v = *(const uint4*)(src + 8);
                v1v = *(const uint4*)(src + 12);
            }
            *(uint4*)&K_lds[n][0] = k0v; *(uint4*)&K_lds[n][4] = k1v;
            int step = n >> 5, ko = n & 31;
            int gq = (ko & 15) >> 2;
            int j = (ko & 3) | ((ko >> 4) << 2);
            unsigned vv[8] = {v0v.x, v0v.y, v0v.z, v0v.w, v1v.x, v1v.y, v1v.z, v1v.w};
            unsigned short* vt = &Vt[step][gq * 16][j];
#pragma unroll
            for (int d = 0; d < 8; d++) {
                vt[(2 * d) * 8]     = (unsigned short)(vv[d] & 0xffff);
                vt[(2 * d + 1) * 8] = (unsigned short)(vv[d] >> 16);
            }
        }
        __syncthreads();

        const int q0base = z * 128 + w * 32;
        bf16x8 qfrag[2];
#pragma unroll
        for (int qt = 0; qt < 2; qt++) {
            int q = q0base + qt * 16 + qloc;
            int pix = (wi * WSZ + (q >> 4)) * WW + wj * WSZ + (q & 15);
            B8 f;
#pragma unroll
            for (int j = 0; j < 4; j++) f.u[j] = 0;
            if (g < 2)
                f.v = *(const bf16x8*)(qkvu + (size_t)pix * 192 + 8 * h + 4 * g);
            qfrag[qt] = f.v;
        }

        f32x4 O[2];
        float lsum[2];
#pragma unroll
        for (int qt = 0; qt < 2; qt++) { O[qt] = zz; lsum[qt] = 0.f; }

        for (int step = 0; step < 18; step++) {
            const int k0 = step * 32;
            bf16x8 kfA, kfB;
            if (g < 2) {
                kfA = *(const bf16x8*)&K_lds[k0 + qloc][4 * g];
                kfB = *(const bf16x8*)&K_lds[k0 + 16 + qloc][4 * g];
            } else {
                B8 zf;
#pragma unroll
                for (int j = 0; j < 4; j++) zf.u[j] = 0;
                kfA = zf.v; kfB = zf.v;
            }
            bf16x8 vfv = *(const bf16x8*)&Vt[step][lane][0];

#pragma unroll
            for (int qt = 0; qt < 2; qt++) {
                int qa = q0base + qt * 16 + qloc;
                const float* bpA = bias1T + ((size_t)h * NKV1 + k0 + 4 * g) * NQ1 + qa;
                const float* bpB = bpA + 16 * NQ1;
                f32x4 cA, cB;
#pragma unroll
                for (int r = 0; r < 4; r++) {
                    cA[r] = bpA[(size_t)r * NQ1];
                    cB[r] = bpB[(size_t)r * NQ1];
                }
                f32x4 sA = __builtin_amdgcn_mfma_f32_16x16x32_bf16(kfA, qfrag[qt], cA, 0, 0, 0);
                f32x4 sB = __builtin_amdgcn_mfma_f32_16x16x32_bf16(kfB, qfrag[qt], cB, 0, 0, 0);
                float pa[4], pb[4];
                float ls = 0.f;
#pragma unroll
                for (int r = 0; r < 4; r++) {
                    pa[r] = exp2f(sA[r]);
                    pb[r] = exp2f(sB[r]);
                    ls += pa[r] + pb[r];
                }
                B8 pf;
                pf.u[0] = cvtpk(pa[0], pa[1]);
                pf.u[1] = cvtpk(pa[2], pa[3]);
                pf.u[2] = cvtpk(pb[0], pb[1]);
                pf.u[3] = cvtpk(pb[2], pb[3]);
                lsum[qt] += ls;
                O[qt] = __builtin_amdgcn_mfma_f32_16x16x32_bf16(vfv, pf.v, O[qt], 0, 0, 0);
            }
        }

#pragma unroll
        for (int qt = 0; qt < 2; qt++) {
            float lt = lsum[qt];
            lt += __shfl_xor(lt, 16);
            lt += __shfl_xor(lt, 32);
            float rl = 1.f / lt;
            int q = q0base + qt * 16 + qloc;
            int pix = (wi * WSZ + (q >> 4)) * WW + wj * WSZ + (q & 15);
            size_t base = (size_t)pix * 128 + h * HD + 4 * g;
#pragma unroll
            for (int r = 0; r < 4; r++)
                xcat[base + r] = O[qt][r] * rl + lnx[base + r];
        }
    } else {
        // ---------------- attn2: 576 patch q x 256 window keys ----------------
        const int bx = blockIdx.x - 288;
        const int win = bx % 144, z = bx / 144;
        const int wi = win / NWIN, wj = win % NWIN;

        {
            int n = tid;
            int pix = (wi * WSZ + (n >> 4)) * WW + wj * WSZ + (n & 15);
            const unsigned* src = qkvu + (size_t)pix * 192 + 128 + 16 * h;
            uint4 k0v = *(const uint4*)(src);
            uint4 k1v = *(const uint4*)(src + 4);
            uint4 v0v = *(const uint4*)(src + 8);
            uint4 v1v = *(const uint4*)(src + 12);
            *(uint4*)&K_lds[n][0] = k0v;
            *(uint4*)&K_lds[n][4] = k1v;
            int step = n >> 5, ko = n & 31;
            int gq = (ko & 15) >> 2;
            int j = (ko & 3) | ((ko >> 4) << 2);
            unsigned vv[8] = {v0v.x, v0v.y, v0v.z, v0v.w, v1v.x, v1v.y, v1v.z, v1v.w};
            unsigned short* vt = &Vt[step][gq * 16][j];
#pragma unroll
            for (int d = 0; d < 8; d++) {
                vt[(2 * d) * 8]     = (unsigned short)(vv[d] & 0xffff);
                vt[(2 * d + 1) * 8] = (unsigned short)(vv[d] >> 16);
            }
        }
        __syncthreads();

        const int q0base = z * 192 + w * 48;
        bf16x8 qfrag[3];
        bool qin[3];
        int qpix[3];
#pragma unroll
        for (int qt = 0; qt < 3; qt++) {
            int qa = q0base + qt * 16 + qloc;
            int gr = wi * WSZ - PADK + qa / OWSZ, gc = wj * WSZ - PADK + qa % OWSZ;
            bool ib = (gr >= 0 && gr < HH && gc >= 0 && gc < WW);
            qin[qt] = ib;
            qpix[qt] = ib ? gr * WW + gc : 0;
            B8 f;
#pragma unroll
            for (int j = 0; j < 4; j++) f.u[j] = 0;
            if (ib && g < 2)
                f.v = *(const bf16x8*)(qkvu + (size_t)qpix[qt] * 192 + 32 + 8 * h + 4 * g);
            qfrag[qt] = f.v;
        }

        f32x4 O[3];
        float lsum[3];
#pragma unroll
        for (int qt = 0; qt < 3; qt++) { O[qt] = zz; lsum[qt] = 0.f; }

        for (int step = 0; step < 8; step++) {
            const int k0 = step * 32;
            bf16x8 kfA, kfB;
            if (g < 2) {
                kfA = *(const bf16x8*)&K_lds[k0 + qloc][4 * g];
                kfB = *(const bf16x8*)&K_lds[k0 + 16 + qloc][4 * g];
            } else {
                B8 zf;
#pragma unroll
                for (int j = 0; j < 4; j++) zf.u[j] = 0;
                kfA = zf.v; kfB = zf.v;
            }
            bf16x8 vfv = *(const bf16x8*)&Vt[step][lane][0];

#pragma unroll
            for (int qt = 0; qt < 3; qt++) {
                int qa = q0base + qt * 16 + qloc;
                const float* bpA = bias2T + ((size_t)h * NQ1 + k0 + 4 * g) * NKV1 + qa;
                const float* bpB = bpA + 16 * NKV1;
                f32x4 cA, cB;
#pragma unroll
                for (int r = 0; r < 4; r++) {
                    cA[r] = bpA[(size_t)r * NKV1];
                    cB[r] = bpB[(size_t)r * NKV1];
                }
                f32x4 sA = __builtin_amdgcn_mfma_f32_16x16x32_bf16(kfA, qfrag[qt], cA, 0, 0, 0);
                f32x4 sB = __builtin_amdgcn_mfma_f32_16x16x32_bf16(kfB, qfrag[qt], cB, 0, 0, 0);
                float pa[4], pb[4];
                float ls = 0.f;
#pragma unroll
                for (int r = 0; r < 4; r++) {
                    pa[r] = exp2f(sA[r]);
                    pb[r] = exp2f(sB[r]);
                    ls += pa[r] + pb[r];
                }
                B8 pf;
                pf.u[0] = cvtpk(pa[0], pa[1]);
                pf.u[1] = cvtpk(pa[2], pa[3]);
                pf.u[2] = cvtpk(pb[0], pb[1]);
                pf.u[3] = cvtpk(pb[2], pb[3]);
                lsum[qt] += ls;
                O[qt] = __builtin_amdgcn_mfma_f32_16x16x32_bf16(vfv, pf.v, O[qt], 0, 0, 0);
            }
        }

#pragma unroll
        for (int qt = 0; qt < 3; qt++) {
            float lt = lsum[qt];
            lt += __shfl_xor(lt, 16);
            lt += __shfl_xor(lt, 32);
            float rl = 1.f / lt;
            int qa = q0base + qt * 16 + qloc;
            size_t obase = ((size_t)win * NKV1 + qa) * C2K + h * HD + 4 * g;
            size_t rbase = (size_t)qpix[qt] * 128 + C2K + h * HD + 4 * g;
#pragma unroll
            for (int r = 0; r < 4; r++)
                bb[obase + r] = O[qt][r] * rl + (qin[qt] ? lnx[rbase + r] : 0.f);
        }
    }
}

// ---------------- fold (gather form, no atomics) ----------------
__global__ void fold_kernel(const float* __restrict__ bb, float* __restrict__ folded)
{
    int idx = blockIdx.x * 256 + threadIdx.x;
    if (idx >= 200 * 200 * 64) return;
    int c = idx & 63;
    int j = (idx >> 6) % 200;
    int i = idx / (64 * 200);
    int ilo = (i > 23) ? ((i - 8) >> 4) : 0;
    int ihi = min(11, i >> 4);
    int jlo = (j > 23) ? ((j - 8) >> 4) : 0;
    int jhi = min(11, j >> 4);
    float s = 0.f;
    for (int wi = ilo; wi <= ihi; wi++)
        for (int wj = jlo; wj <= jhi; wj++) {
            int p = (i - wi * 16) * OWSZ + (j - wj * 16);
            s += bb[((size_t)(wi * NWIN + wj) * NKV1 + p) * C2K + c];
        }
    folded[idx] = s;
}

// ---------------- bicubic resize 200->192 ----------------
__device__ __forceinline__ float cubicw(float x)
{
    float ax = fabsf(x);
    const float A = -0.75f;
    if (ax <= 1.f) return ((A + 2.f) * ax - (A + 3.f)) * ax * ax + 1.f;
    if (ax < 2.f)  return A * (ax * (ax * (ax - 5.f) + 8.f) - 4.f);
    return 0.f;
}

__global__ void resize_kernel(const float* __restrict__ folded, float* __restrict__ xcat)
{
    int idx = blockIdx.x * 256 + threadIdx.x;
    if (idx >= HH * WW * C2K) return;
    int c = idx & 63;
    int p = (idx >> 6) % WW;
    int o = idx / (C2K * WW);
    const float ratio = 200.f / 192.f;
    float sr = (o + 0.5f) * ratio - 0.5f;
    float sc = (p + 0.5f) * ratio - 0.5f;
    int fr = (int)floorf(sr), fcc = (int)floorf(sc);
    float wc[4]; int ic[4];
#pragma unroll
    for (int u = 0; u < 4; u++) {
        int jj = fcc - 1 + u;
        wc[u] = cubicw(sc - (float)jj);
        ic[u] = min(max(jj, 0), 199);
    }
    float acc = 0.f;
#pragma unroll
    for (int t = 0; t < 4; t++) {
        int ii = fr - 1 + t;
        float wr = cubicw(sr - (float)ii);
        int ir = min(max(ii, 0), 199);
        const float* rowp = folded + ((size_t)ir * 200) * 64 + c;
        float rs = 0.f;
#pragma unroll
        for (int u = 0; u < 4; u++) rs += wc[u] * rowp[(size_t)ic[u] * 64];
        acc += wr * rs;
    }
    xcat[(size_t)(o * WW + p) * 128 + C2K + c] = acc;
}

// ---------------- proj GEMM + residual + fused LN2 -> x_buf(f32) and y(bf16) ----------------
__launch_bounds__(256)
__global__ void proj_ln2(const float* __restrict__ A1,
                         const bf16* __restrict__ WT,
                         const float* __restrict__ bias,
                         const float* __restrict__ R,
                         const float* __restrict__ ln2w, const float* __restrict__ ln2b,
                         float* __restrict__ xbuf, unsigned* __restrict__ ybf)
{
    __shared__ float psum[16][16];
    __shared__ float psq[16][16];
    __shared__ float mu_s[16], inv_s[16];

    const int tid = threadIdx.x;
    const int lane = tid & 63, w = tid >> 6;
    const int g = lane >> 4, nl = lane & 15;

    bf16x8 wf[2][4];
#pragma unroll
    for (int t = 0; t < 2; t++) {
        const bf16* wp = WT + (size_t)((w * 2 + t) * 16 + nl) * 128;
#pragma unroll
        for (int ks = 0; ks < 4; ks++)
            wf[t][ks] = *(const bf16x8*)(wp + ks * 32 + 8 * g);
    }

    const int row = (blockIdx.x * 4 + blockIdx.y) * 16 + nl;
    bf16x8 xf[4];
    const float* ap = A1 + (size_t)row * 128 + 8 * g;
#pragma unroll
    for (int ks = 0; ks < 4; ks++) {
        float4 v0 = *(const float4*)(ap + ks * 32);
        float4 v1 = *(const float4*)(ap + ks * 32 + 4);
        B8 f;
        f.u[0] = cvtpk(v0.x, v0.y);
        f.u[1] = cvtpk(v0.z, v0.w);
        f.u[2] = cvtpk(v1.x, v1.y);
        f.u[3] = cvtpk(v1.z, v1.w);
        xf[ks] = f.v;
    }

    const f32x4 zz = {0.f, 0.f, 0.f, 0.f};
    f32x4 acc[2];
    acc[0] = zz; acc[1] = zz;
#pragma unroll
    for (int ks = 0; ks < 4; ks++) {
        acc[0] = __builtin_amdgcn_mfma_f32_16x16x32_bf16(wf[0][ks], xf[ks], acc[0], 0, 0, 0);
        acc[1] = __builtin_amdgcn_mfma_f32_16x16x32_bf16(wf[1][ks], xf[ks], acc[1], 0, 0, 0);
    }

    float o[2][4];
    float s = 0.f, sq = 0.f;
#pragma unroll
    for (int t = 0; t < 2; t++) {
        int n0t = (w * 2 + t) * 16 + 4 * g;
        float4 bv = *(const float4*)(bias + n0t);
        float4 rv = *(const float4*)(R + (size_t)row * 128 + n0t);
        o[t][0] = acc[t][0] + bv.x + rv.x;
        o[t][1] = acc[t][1] + bv.y + rv.y;
        o[t][2] = acc[t][2] + bv.z + rv.z;
        o[t][3] = acc[t][3] + bv.w + rv.w;
#pragma unroll
        for (int r = 0; r < 4; r++) { s += o[t][r]; sq += o[t][r] * o[t][r]; }
    }
    psum[nl][w * 4 + g] = s;
    psq[nl][w * 4 + g] = sq;
    __syncthreads();
    if (tid < 16) {
        float ts = 0.f, tq = 0.f;
#pragma unroll
        for (int i = 0; i < 16; i++) { ts += psum[tid][i]; tq += psq[tid][i]; }
        float mu = ts * 0.0078125f;
        float var = fmaxf(tq * 0.0078125f - mu * mu, 0.f);
        mu_s[tid] = mu;
        inv_s[tid] = 1.0f / sqrtf(var + 1e-5f);
    }
    __syncthreads();

    float mu = mu_s[nl], inv = inv_s[nl];
#pragma unroll
    for (int t = 0; t < 2; t++) {
        int n0t = (w * 2 + t) * 16 + 4 * g;
        *(float4*)(xbuf + (size_t)row * 128 + n0t) = make_float4(o[t][0], o[t][1], o[t][2], o[t][3]);
        float4 gw = *(const float4*)(ln2w + n0t);
        float4 gb = *(const float4*)(ln2b + n0t);
        float y0 = (o[t][0] - mu) * inv * gw.x + gb.x;
        float y1 = (o[t][1] - mu) * inv * gw.y + gb.y;
        float y2 = (o[t][2] - mu) * inv * gw.z + gb.z;
        float y3 = (o[t][3] - mu) * inv * gw.w + gb.w;
        uint2 yo;
        yo.x = cvtpk(y0, y1);
        yo.y = cvtpk(y2, y3);
        *(uint2*)(ybf + (size_t)row * 64 + (n0t >> 1)) = yo;
    }
}

// ---------------- fc1 GEMM (A bf16) + fused sgn-LN -> x1b (bf16) | x2b (LN'd bf16) ----------------
__launch_bounds__(256)
__global__ void fc1_sgn(const unsigned* __restrict__ ybf,
                        const bf16* __restrict__ WT,
                        const float* __restrict__ bias,
                        const float* __restrict__ sgnw, const float* __restrict__ sgnb,
                        unsigned* __restrict__ x1b, unsigned* __restrict__ x2b)
{
    __shared__ float psum[16][8];
    __shared__ float psq[16][8];
    __shared__ float mu_s[16], inv_s[16];

    const int tid = threadIdx.x;
    const int lane = tid & 63, w = tid >> 6;
    const int g = lane >> 4, nl = lane & 15;

    bf16x8 wf[4][4];
#pragma unroll
    for (int t = 0; t < 4; t++) {
        const bf16* wp = WT + (size_t)((w * 4 + t) * 16 + nl) * 128;
#pragma unroll
        for (int ks = 0; ks < 4; ks++)
            wf[t][ks] = *(const bf16x8*)(wp + ks * 32 + 8 * g);
    }

    const int row = (blockIdx.x * 4 + blockIdx.y) * 16 + nl;
    bf16x8 xf[4];
    const unsigned* ap = ybf + (size_t)row * 64 + 4 * g;
#pragma unroll
    for (int ks = 0; ks < 4; ks++)
        xf[ks] = *(const bf16x8*)(ap + ks * 16);

    const f32x4 zz = {0.f, 0.f, 0.f, 0.f};
    f32x4 acc[4];
#pragma unroll
    for (int t = 0; t < 4; t++) acc[t] = zz;
#pragma unroll
    for (int ks = 0; ks < 4; ks++)
#pragma unroll
        for (int t = 0; t < 4; t++)
            acc[t] = __builtin_amdgcn_mfma_f32_16x16x32_bf16(wf[t][ks], xf[ks], acc[t], 0, 0, 0);

    float o[4][4];
    float s = 0.f, sq = 0.f;
#pragma unroll
    for (int t = 0; t < 4; t++) {
        int n0t = (w * 4 + t) * 16 + 4 * g;
        float4 bv = *(const float4*)(bias + n0t);
        o[t][0] = acc[t][0] + bv.x;
        o[t][1] = acc[t][1] + bv.y;
        o[t][2] = acc[t][2] + bv.z;
        o[t][3] = acc[t][3] + bv.w;
    }
    if (w >= 2) {
#pragma unroll
        for (int t = 0; t < 4; t++)
#pragma unroll
            for (int r = 0; r < 4; r++) { s += o[t][r]; sq += o[t][r] * o[t][r]; }
        psum[nl][(w - 2) * 4 + g] = s;
        psq[nl][(w - 2) * 4 + g] = sq;
    }
    __syncthreads();
    if (tid < 16) {
        float ts = 0.f, tq = 0.f;
#pragma unroll
        for (int i = 0; i < 8; i++) { ts += psum[tid][i]; tq += psq[tid][i]; }
        float mu = ts * 0.0078125f;
        float var = fmaxf(tq * 0.0078125f - mu * mu, 0.f);
        mu_s[tid] = mu;
        inv_s[tid] = 1.0f / sqrtf(var + 1e-5f);
    }
    __syncthreads();

    if (w < 2) {
#pragma unroll
        for (int t = 0; t < 4; t++) {
            int n0t = (w * 4 + t) * 16 + 4 * g;   // 0..127
            uint2 xo;
            xo.x = cvtpk(o[t][0], o[t][1]);
            xo.y = cvtpk(o[t][2], o[t][3]);
            *(uint2*)(x1b + (size_t)row * 64 + (n0t >> 1)) = xo;
        }
    } else {
        float mu = mu_s[nl], inv = inv_s[nl];
#pragma unroll
        for (int t = 0; t < 4; t++) {
            int n0t = (w * 4 + t) * 16 + 4 * g;
            int m0t = n0t - 128;                  // 0..127
            float4 gw = *(const float4*)(sgnw + m0t);
            float4 gb = *(const float4*)(sgnb + m0t);
            float y0 = (o[t][0] - mu) * inv * gw.x + gb.x;
            float y1 = (o[t][1] - mu) * inv * gw.y + gb.y;
            float y2 = (o[t][2] - mu) * inv * gw.z + gb.z;
            float y3 = (o[t][3] - mu) * inv * gw.w + gb.w;
            uint2 xo;
            xo.x = cvtpk(y0, y1);
            xo.y = cvtpk(y2, y3);
            *(uint2*)(x2b + (size_t)row * 64 + (m0t >> 1)) = xo;
        }
    }
}

// ---------------- depthwise 3x3 conv on bf16 x2, fused x1 multiply -> ab (bf16), 2 ch/thread ----------------
__global__ void dwconv_kernel(const unsigned* __restrict__ x2b,
                              const unsigned* __restrict__ x1b,
                              const float* __restrict__ conv_w,
                              const float* __restrict__ conv_b,
                              unsigned* __restrict__ ab)
{
    int idx = blockIdx.x * 256 + threadIdx.x;
    if (idx >= NTOK * 64) return;
    int cp = idx & 63, t = idx >> 6;
    int i = t / WW, j = t % WW;
    int ch = cp * 2;
    float a0 = conv_b[ch], a1 = conv_b[ch + 1];
#pragma unroll
    for (int a = 0; a < 3; a++) {
        int ii = i + a - 1;
        if (ii < 0 || ii >= HH) continue;
#pragma unroll
        for (int b = 0; b < 3; b++) {
            int jj = j + b - 1;
            if (jj < 0 || jj >= WW) continue;
            unsigned v = x2b[(size_t)(ii * WW + jj) * 64 + cp];
            a0 += conv_w[ch * 9 + a * 3 + b] * bflo(v);
            a1 += conv_w[(ch + 1) * 9 + a * 3 + b] * bfhi(v);
        }
    }
    unsigned m = x1b[(size_t)t * 64 + cp];
    ab[(size_t)t * 64 + cp] = cvtpk(bflo(m) * a0, bfhi(m) * a1);
}

// ---------------- fc2 GEMM (A bf16 direct) + bias + residual -> out f32, N=128 ----------------
__launch_bounds__(256)
__global__ void gemm_bfA(const unsigned* __restrict__ Au,
                         const bf16* __restrict__ WT,
                         const float* __restrict__ bias,
                         const float* __restrict__ R,
                         float* __restrict__ C)
{
    const int tid = threadIdx.x;
    const int lane = tid & 63, w = tid >> 6;
    const int g = lane >> 4, nl = lane & 15;

    bf16x8 wf[2][4];
#pragma unroll
    for (int t = 0; t < 2; t++) {
        const bf16* wp = WT + (size_t)((w * 2 + t) * 16 + nl) * 128;
#pragma unroll
        for (int ks = 0; ks < 4; ks++)
            wf[t][ks] = *(const bf16x8*)(wp + ks * 32 + 8 * g);
    }

    const int row = (blockIdx.x * 4 + blockIdx.y) * 16 + nl;
    bf16x8 xf[4];
    const unsigned* ap = Au + (size_t)row * 64 + 4 * g;
#pragma unroll
    for (int ks = 0; ks < 4; ks++)
        xf[ks] = *(const bf16x8*)(ap + ks * 16);

    const f32x4 zz = {0.f, 0.f, 0.f, 0.f};
    f32x4 acc[2];
    acc[0] = zz; acc[1] = zz;
#pragma unroll
    for (int ks = 0; ks < 4; ks++) {
        acc[0] = __builtin_amdgcn_mfma_f32_16x16x32_bf16(wf[0][ks], xf[ks], acc[0], 0, 0, 0);
        acc[1] = __builtin_amdgcn_mfma_f32_16x16x32_bf16(wf[1][ks], xf[ks], acc[1], 0, 0, 0);
    }

#pragma unroll
    for (int t = 0; t < 2; t++) {
        const int n0t = (w * 2 + t) * 16 + 4 * g;
        float4 bv = *(const float4*)(bias + n0t);
        float4 rv = *(const float4*)(R + (size_t)row * 128 + n0t);
        float4 o;
        o.x = acc[t][0] + bv.x + rv.x;
        o.y = acc[t][1] + bv.y + rv.y;
        o.z = acc[t][2] + bv.z + rv.z;
        o.w = acc[t][3] + bv.w + rv.w;
        *(float4*)(C + (size_t)row * 128 + n0t) = o;
    }
}

extern "C" void kernel_launch(void* const* d_in, const int* in_sizes, int n_in,
                              void* d_out, int out_size, void* d_ws, size_t ws_size,
                              hipStream_t stream)
{
    (void)in_sizes; (void)n_in; (void)out_size; (void)ws_size;
    const float* x_tkn  = (const float*)d_in[0];
    const float* ln1_w  = (const float*)d_in[1];
    const float* ln1_b  = (const float*)d_in[2];
    const float* q1_w   = (const float*)d_in[3];
    const float* kv1_w  = (const float*)d_in[4];
    const float* rpb1   = (const float*)d_in[5];
    const float* q2_w   = (const float*)d_in[6];
    const float* kv2_w  = (const float*)d_in[7];
    const float* rpb2   = (const float*)d_in[8];
    const float* proj_w = (const float*)d_in[9];
    const float* proj_b = (const float*)d_in[10];
    const float* ln2_w  = (const float*)d_in[11];
    const float* ln2_b  = (const float*)d_in[12];
    const float* fc1_w  = (const float*)d_in[13];
    const float* fc1_b  = (const float*)d_in[14];
    const float* sgn_w  = (const float*)d_in[15];
    const float* sgn_b  = (const float*)d_in[16];
    const float* conv_w = (const float*)d_in[17];
    const float* conv_b = (const float*)d_in[18];
    const float* fc2_w  = (const float*)d_in[19];
    const float* fc2_b  = (const float*)d_in[20];
    const int*   rpi    = (const int*)d_in[21];

    float* ws = (float*)d_ws;
    // layout (float units); ordered-alias verified (same as rounds 12-15):
    float* lnx    = ws;                      // 0 .. 4,718,592    (LN1 out; later x_buf)
    float* xcat   = ws + 4718592;            // .. 9,437,184      (x_cat)
    float* bbuf   = ws + 9437184;            // .. 14,745,600     (bb; later ybf)
    bf16*  projT  = (bf16*)(ws + 14155776);  // bb tail, written AFTER fold
    bf16*  fc1T   = (bf16*)(ws + 14163968);
    bf16*  fc2T   = (bf16*)(ws + 14180352);
    float* bias1T = ws + 14745600;           // .. 15,335,424 (dead after attn)
    float* bias2T = ws + 17104896;           // .. 17,694,720 (dead after attn)
    float* qkv    = ws + 17694720;           // .. 24,772,608 (192 uints/row; dead after attn)
    bf16*  wcombT = (bf16*)(ws + 24772608);  // .. 24,797,184 (dead after qkv gemm)
    float* foldp  = ws + 17694720;           // aliases qkv (dead after resize)
    unsigned* ybf = (unsigned*)bbuf;         // bb dead after fold
    unsigned* x1b = (unsigned*)(ws + 14745600);  // .. 17,104,896
    unsigned* x2b = (unsigned*)(ws + 17104896);  // .. 19,464,192
    unsigned* ab  = (unsigned*)(ws + 19464192);  // .. 21,823,488
    float* out    = (float*)d_out;

    // 1. weight + bias prep
    wcombT_kernel<<<(384 * 128) / 256, 256, 0, stream>>>(q1_w, kv1_w, q2_w, kv2_w, wcombT);
    bias1_kernel<<<(H2K * NKV1 * NQ1) / 256, 256, 0, stream>>>(rpb1, rpi, bias1T);
    bias2_kernel<<<(H2K * NQ1 * NKV1) / 256, 256, 0, stream>>>(rpb2, rpi, bias2T);
    // 2. qkv = LN1(x_tkn) @ Wcomb (N=384) -> bf16; also writes lnx f32
    gemm_qkv<<<dim3(NTOK / 64, 4), 256, 0, stream>>>(x_tkn, ln1_w, ln1_b, wcombT,
                                                     (unsigned*)qkv, lnx);
    // 3. fused attention (attn1 + attn2, V transposed, bias as MFMA C)
    attn_fused<<<dim3(720, 4), 256, 0, stream>>>((const unsigned*)qkv, lnx,
                                                 bias1T, bias2T, xcat, bbuf);
    // 4. fold bb -> folded (200x200x64)
    fold_kernel<<<(200 * 200 * 64) / 256, 256, 0, stream>>>(bbuf, foldp);
    // 4b. transpose fc weights into bb tail (bb dead)
    wtrans_kernel<<<(128 * 128) / 256, 256, 0, stream>>>(proj_w, 128, projT);
    wtrans_kernel<<<(256 * 128) / 256, 256, 0, stream>>>(fc1_w, 256, fc1T);
    wtrans_kernel<<<(128 * 128) / 256, 256, 0, stream>>>(fc2_w, 128, fc2T);
    // 5. bicubic resize -> xcat[:, 64:128]
    resize_kernel<<<(HH * WW * C2K) / 256, 256, 0, stream>>>(foldp, xcat);
    // 6. proj + residual + fused LN2: x_buf(lnx, f32) and y(ybf, bf16)
    proj_ln2<<<dim3(NTOK / 64, 4), 256, 0, stream>>>(xcat, projT, proj_b, x_tkn,
                                                     ln2_w, ln2_b, lnx, ybf);
    // 7. fc1 + fused sgn-LN -> x1b, x2b (compact bf16)
    fc1_sgn<<<dim3(NTOK / 64, 4), 256, 0, stream>>>(ybf, fc1T, fc1_b, sgn_w, sgn_b, x1b, x2b);
    // 8. depthwise conv + x1 multiply -> ab (bf16), 2 ch/thread
    dwconv_kernel<<<(NTOK * 64) / 256, 256, 0, stream>>>(x2b, x1b, conv_w, conv_b, ab);
    // 9. fc2: out = ab @ fc2_w + fc2_b + x_buf
    gemm_bfA<<<dim3(NTOK / 64, 4), 256, 0, stream>>>(ab, fc2T, fc2_b, lnx, out);
}

// Round 17
// 273.414 us; speedup vs baseline: 1.0268x; 1.0268x over previous
//
#include <hip/hip_runtime.h>
#include <hip/hip_bf16.h>

#define HH 192
#define WW 192
#define NWIN 12
#define WSZ 16
#define OWSZ 24
#define PADK 4
#define NQ1 256      // WS*WS
#define NKV1 576     // OWS*OWS
#define C2K 64
#define H2K 4
#define HD 16        // head dim
#define NTOK (HH*WW)
#define LOG2E 1.4426950408889634f
#define QSCALE (0.25f * LOG2E)

typedef __hip_bfloat16 bf16;
typedef __attribute__((ext_vector_type(8))) short bf16x8;
typedef __attribute__((ext_vector_type(4))) float f32x4;

union B8 { short s[8]; bf16x8 v; unsigned u[4]; };

__device__ __forceinline__ unsigned cvtpk(float lo, float hi)
{
    unsigned r;
    asm("v_cvt_pk_bf16_f32 %0, %1, %2" : "=v"(r) : "v"(lo), "v"(hi));
    return r;
}
__device__ __forceinline__ float bfu2f(unsigned short u)
{
    return __uint_as_float(((unsigned)u) << 16);
}

// ---------------- combined projection weight, transposed bf16, PERMUTED columns ----------------
__global__ void wcombT_kernel(const float* __restrict__ q1_w, const float* __restrict__ kv1_w,
                              const float* __restrict__ q2_w, const float* __restrict__ kv2_w,
                              bf16* __restrict__ WT)
{
    int idx = blockIdx.x * 256 + threadIdx.x;
    if (idx >= 384 * 128) return;
    int cp = idx >> 7, r = idx & 127;
    int c;   // original semantic column
    if (cp < 64) c = cp;
    else if (cp < 128) c = 192 + (cp - 64);
    else if (cp < 256) {
        int j = cp - 128, h = j >> 5, m = j & 31;
        c = (m < 16) ? (64 + 16 * h + m) : (128 + 16 * h + (m - 16));
    } else {
        int j = cp - 256, h = j >> 5, m = j & 31;
        c = (m < 16) ? (256 + 16 * h + m) : (320 + 16 * h + (m - 16));
    }
    float v = 0.f;
    if (c < 64)       { if (r < 64)  v = q1_w[r * 64 + c] * QSCALE; }
    else if (c < 192) { if (r >= 64) v = kv1_w[(r - 64) * 128 + (c - 64)]; }
    else if (c < 256) { if (r >= 64) v = q2_w[(r - 64) * 64 + (c - 192)] * QSCALE; }
    else              { if (r < 64)  v = kv2_w[r * 128 + (c - 256)]; }
    WT[idx] = __float2bfloat16(v);
}

// ---------------- generic weight transpose to bf16: dst[n][k] = src[k][n], K=128 ----------------
__global__ void wtrans_kernel(const float* __restrict__ src, int N, bf16* __restrict__ dst)
{
    int idx = blockIdx.x * 256 + threadIdx.x;
    if (idx >= N * 128) return;
    int n = idx >> 7, k = idx & 127;
    dst[idx] = __float2bfloat16(src[(size_t)k * N + n]);
}

// ---------------- bias transposes (pre-scaled by log2(e)) ----------------
__global__ void bias1_kernel(const float* __restrict__ rpb1, const int* __restrict__ rpi,
                             float* __restrict__ biasT)   // [h][n][q]
{
    int idx = blockIdx.x * 256 + threadIdx.x;
    if (idx >= H2K * NKV1 * NQ1) return;
    int q = idx & 255;
    int n = (idx >> 8) % NKV1;
    int h = idx / (NKV1 * NQ1);
    biasT[idx] = rpb1[rpi[q * NKV1 + n] * H2K + h] * LOG2E;
}

__global__ void bias2_kernel(const float* __restrict__ rpb2, const int* __restrict__ rpi,
                             float* __restrict__ biasT)   // [h][k][q]
{
    int idx = blockIdx.x * 256 + threadIdx.x;
    if (idx >= H2K * NQ1 * NKV1) return;
    int q = idx % NKV1;
    int k = (idx / NKV1) % NQ1;
    int h = idx / (NKV1 * NQ1);
    biasT[idx] = rpb2[rpi[k * NKV1 + q] * H2K + h] * LOG2E;
}

// ---------------- qkv GEMM (N=384) with fused LN1 -> qkv bf16 (192-uint rows) + lnx f32 ----------------
__launch_bounds__(256)
__global__ void gemm_qkv(const float* __restrict__ x_tkn,
                         const float* __restrict__ ln1w, const float* __restrict__ ln1b,
                         const bf16* __restrict__ WT,
                         unsigned* __restrict__ qkvo, float* __restrict__ lnx)
{
    const int tid = threadIdx.x;
    const int lane = tid & 63, w = tid >> 6;
    const int g = lane >> 4, nl = lane & 15;

    bf16x8 wf[6][4];
#pragma unroll
    for (int t = 0; t < 6; t++) {
        const bf16* wp = WT + (size_t)((w * 6 + t) * 16 + nl) * 128;
#pragma unroll
        for (int ks = 0; ks < 4; ks++)
            wf[t][ks] = *(const bf16x8*)(wp + ks * 32 + 8 * g);
    }

    const int row = (blockIdx.x * 4 + blockIdx.y) * 16 + nl;
    const float* ap = x_tkn + (size_t)row * 128 + 8 * g;

    float av[4][8];
    float s = 0.f, sq = 0.f;
#pragma unroll
    for (int ks = 0; ks < 4; ks++) {
        float4 v0 = *(const float4*)(ap + ks * 32);
        float4 v1 = *(const float4*)(ap + ks * 32 + 4);
        av[ks][0] = v0.x; av[ks][1] = v0.y; av[ks][2] = v0.z; av[ks][3] = v0.w;
        av[ks][4] = v1.x; av[ks][5] = v1.y; av[ks][6] = v1.z; av[ks][7] = v1.w;
#pragma unroll
        for (int j = 0; j < 8; j++) { s += av[ks][j]; sq += av[ks][j] * av[ks][j]; }
    }
    s  += __shfl_xor(s, 16);  s  += __shfl_xor(s, 32);
    sq += __shfl_xor(sq, 16); sq += __shfl_xor(sq, 32);
    float mu  = s * 0.0078125f;
    float var = fmaxf(sq * 0.0078125f - mu * mu, 0.f);
    float inv = 1.0f / sqrtf(var + 1e-5f);

    bf16x8 xf[4];
#pragma unroll
    for (int ks = 0; ks < 4; ks++) {
        int col = ks * 32 + 8 * g;
        float4 g0 = *(const float4*)(ln1w + col);
        float4 g1 = *(const float4*)(ln1w + col + 4);
        float4 b0 = *(const float4*)(ln1b + col);
        float4 b1 = *(const float4*)(ln1b + col + 4);
        float nv[8];
        nv[0] = (av[ks][0] - mu) * inv * g0.x + b0.x;
        nv[1] = (av[ks][1] - mu) * inv * g0.y + b0.y;
        nv[2] = (av[ks][2] - mu) * inv * g0.z + b0.z;
        nv[3] = (av[ks][3] - mu) * inv * g0.w + b0.w;
        nv[4] = (av[ks][4] - mu) * inv * g1.x + b1.x;
        nv[5] = (av[ks][5] - mu) * inv * g1.y + b1.y;
        nv[6] = (av[ks][6] - mu) * inv * g1.z + b1.z;
        nv[7] = (av[ks][7] - mu) * inv * g1.w + b1.w;
        if (w == 0) {
            float* lp = lnx + (size_t)row * 128 + col;
            *(float4*)lp       = make_float4(nv[0], nv[1], nv[2], nv[3]);
            *(float4*)(lp + 4) = make_float4(nv[4], nv[5], nv[6], nv[7]);
        }
        B8 f;
        f.u[0] = cvtpk(nv[0], nv[1]);
        f.u[1] = cvtpk(nv[2], nv[3]);
        f.u[2] = cvtpk(nv[4], nv[5]);
        f.u[3] = cvtpk(nv[6], nv[7]);
        xf[ks] = f.v;
    }

    const f32x4 zz = {0.f, 0.f, 0.f, 0.f};
    f32x4 acc[6];
#pragma unroll
    for (int t = 0; t < 6; t++) acc[t] = zz;
#pragma unroll
    for (int ks = 0; ks < 4; ks++)
#pragma unroll
        for (int t = 0; t < 6; t++)
            acc[t] = __builtin_amdgcn_mfma_f32_16x16x32_bf16(wf[t][ks], xf[ks], acc[t], 0, 0, 0);

#pragma unroll
    for (int t = 0; t < 6; t++) {
        int n0t = (w * 6 + t) * 16 + 4 * g;
        uint2 o;
        o.x = cvtpk(acc[t][0], acc[t][1]);
        o.y = cvtpk(acc[t][2], acc[t][3]);
        *(uint2*)(qkvo + (size_t)row * 192 + (n0t >> 1)) = o;
    }
}

// ---------------- fused attention. grid (720, 4). V transposed; bias as MFMA C, prefetched ----------------
// qkv row (uints): [q1:0-31][q2:32-63][KV1:64-127 (head h at 64+16h: K8|V8)][KV2:128-191]
__launch_bounds__(256)
__global__ void attn_fused(const unsigned* __restrict__ qkvu,
                           const float* __restrict__ lnx,
                           const float* __restrict__ bias1T,   // [h][n][q]
                           const float* __restrict__ bias2T,   // [h][k][q]
                           float* __restrict__ xcat,
                           float* __restrict__ bb)
{
    __shared__ unsigned K_lds[NKV1][10];
    __shared__ unsigned short Vt[18][64][8];

    const int h = blockIdx.y;
    const int tid = threadIdx.x;
    const int lane = tid & 63, w = tid >> 6;
    const int g = lane >> 4, qloc = lane & 15;
    const f32x4 zz = {0.f, 0.f, 0.f, 0.f};

    if (blockIdx.x < 288) {
        // ---------------- attn1: 256 window q x 576 patch keys ----------------
        const int win = blockIdx.x % 144, z = blockIdx.x / 144;
        const int wi = win / NWIN, wj = win % NWIN;

        for (int n = tid; n < NKV1; n += 256) {
            int rr = wi * WSZ - PADK + n / OWSZ, cc = wj * WSZ - PADK + n % OWSZ;
            bool ib = (rr >= 0 && rr < HH && cc >= 0 && cc < WW);
            uint4 k0v = make_uint4(0, 0, 0, 0), k1v = k0v, v0v = k0v, v1v = k0v;
            if (ib) {
                const unsigned* src = qkvu + (size_t)(rr * WW + cc) * 192 + 64 + 16 * h;
                k0v = *(const uint4*)(src);
                k1v = *(const uint4*)(src + 4);
                v0v = *(const uint4*)(src + 8);
                v1v = *(const uint4*)(src + 12);
            }
            *(uint4*)&K_lds[n][0] = k0v; *(uint4*)&K_lds[n][4] = k1v;
            int step = n >> 5, ko = n & 31;
            int gq = (ko & 15) >> 2;
            int j = (ko & 3) | ((ko >> 4) << 2);
            unsigned vv[8] = {v0v.x, v0v.y, v0v.z, v0v.w, v1v.x, v1v.y, v1v.z, v1v.w};
            unsigned short* vt = &Vt[step][gq * 16][j];
#pragma unroll
            for (int d = 0; d < 8; d++) {
                vt[(2 * d) * 8]     = (unsigned short)(vv[d] & 0xffff);
                vt[(2 * d + 1) * 8] = (unsigned short)(vv[d] >> 16);
            }
        }
        __syncthreads();

        const int q0base = z * 128 + w * 32;
        bf16x8 qfrag[2];
#pragma unroll
        for (int qt = 0; qt < 2; qt++) {
            int q = q0base + qt * 16 + qloc;
            int pix = (wi * WSZ + (q >> 4)) * WW + wj * WSZ + (q & 15);
            B8 f;
#pragma unroll
            for (int j = 0; j < 4; j++) f.u[j] = 0;
            if (g < 2)
                f.v = *(const bf16x8*)(qkvu + (size_t)pix * 192 + 8 * h + 4 * g);
            qfrag[qt] = f.v;
        }

        f32x4 O[2];
        float lsum[2];
#pragma unroll
        for (int qt = 0; qt < 2; qt++) { O[qt] = zz; lsum[qt] = 0.f; }

        // bias prefetch: load step 0
        f32x4 cA[2], cB[2];
#pragma unroll
        for (int qt = 0; qt < 2; qt++) {
            int qa = q0base + qt * 16 + qloc;
            const float* bp = bias1T + ((size_t)h * NKV1 + 4 * g) * NQ1 + qa;
#pragma unroll
            for (int r = 0; r < 4; r++) {
                cA[qt][r] = bp[(size_t)r * NQ1];
                cB[qt][r] = bp[(size_t)(16 + r) * NQ1];
            }
        }

        for (int step = 0; step < 18; step++) {
            const int k0 = step * 32;
            bf16x8 kfA, kfB;
            if (g < 2) {
                kfA = *(const bf16x8*)&K_lds[k0 + qloc][4 * g];
                kfB = *(const bf16x8*)&K_lds[k0 + 16 + qloc][4 * g];
            } else {
                B8 zf;
#pragma unroll
                for (int j = 0; j < 4; j++) zf.u[j] = 0;
                kfA = zf.v; kfB = zf.v;
            }
            bf16x8 vfv = *(const bf16x8*)&Vt[step][lane][0];

            // issue bias loads for step+1
            f32x4 nA[2], nB[2];
            if (step < 17) {
#pragma unroll
                for (int qt = 0; qt < 2; qt++) {
                    int qa = q0base + qt * 16 + qloc;
                    const float* bp = bias1T + ((size_t)h * NKV1 + k0 + 32 + 4 * g) * NQ1 + qa;
#pragma unroll
                    for (int r = 0; r < 4; r++) {
                        nA[qt][r] = bp[(size_t)r * NQ1];
                        nB[qt][r] = bp[(size_t)(16 + r) * NQ1];
                    }
                }
            }

#pragma unroll
            for (int qt = 0; qt < 2; qt++) {
                f32x4 sA = __builtin_amdgcn_mfma_f32_16x16x32_bf16(kfA, qfrag[qt], cA[qt], 0, 0, 0);
                f32x4 sB = __builtin_amdgcn_mfma_f32_16x16x32_bf16(kfB, qfrag[qt], cB[qt], 0, 0, 0);
                float pa[4], pb[4];
                float ls = 0.f;
#pragma unroll
                for (int r = 0; r < 4; r++) {
                    pa[r] = exp2f(sA[r]);
                    pb[r] = exp2f(sB[r]);
                    ls += pa[r] + pb[r];
                }
                B8 pf;
                pf.u[0] = cvtpk(pa[0], pa[1]);
                pf.u[1] = cvtpk(pa[2], pa[3]);
                pf.u[2] = cvtpk(pb[0], pb[1]);
                pf.u[3] = cvtpk(pb[2], pb[3]);
                lsum[qt] += ls;
                O[qt] = __builtin_amdgcn_mfma_f32_16x16x32_bf16(vfv, pf.v, O[qt], 0, 0, 0);
            }
            if (step < 17) {
#pragma unroll
                for (int qt = 0; qt < 2; qt++) { cA[qt] = nA[qt]; cB[qt] = nB[qt]; }
            }
        }

#pragma unroll
        for (int qt = 0; qt < 2; qt++) {
            float lt = lsum[qt];
            lt += __shfl_xor(lt, 16);
            lt += __shfl_xor(lt, 32);
            float rl = 1.f / lt;
            int q = q0base + qt * 16 + qloc;
            int pix = (wi * WSZ + (q >> 4)) * WW + wj * WSZ + (q & 15);
            size_t base = (size_t)pix * 128 + h * HD + 4 * g;
#pragma unroll
            for (int r = 0; r < 4; r++)
                xcat[base + r] = O[qt][r] * rl + lnx[base + r];
        }
    } else {
        // ---------------- attn2: 576 patch q x 256 window keys ----------------
        const int bx = blockIdx.x - 288;
        const int win = bx % 144, z = bx / 144;
        const int wi = win / NWIN, wj = win % NWIN;

        {
            int n = tid;
            int pix = (wi * WSZ + (n >> 4)) * WW + wj * WSZ + (n & 15);
            const unsigned* src = qkvu + (size_t)pix * 192 + 128 + 16 * h;
            uint4 k0v = *(const uint4*)(src);
            uint4 k1v = *(const uint4*)(src + 4);
            uint4 v0v = *(const uint4*)(src + 8);
            uint4 v1v = *(const uint4*)(src + 12);
            *(uint4*)&K_lds[n][0] = k0v;
            *(uint4*)&K_lds[n][4] = k1v;
            int step = n >> 5, ko = n & 31;
            int gq = (ko & 15) >> 2;
            int j = (ko & 3) | ((ko >> 4) << 2);
            unsigned vv[8] = {v0v.x, v0v.y, v0v.z, v0v.w, v1v.x, v1v.y, v1v.z, v1v.w};
            unsigned short* vt = &Vt[step][gq * 16][j];
#pragma unroll
            for (int d = 0; d < 8; d++) {
                vt[(2 * d) * 8]     = (unsigned short)(vv[d] & 0xffff);
                vt[(2 * d + 1) * 8] = (unsigned short)(vv[d] >> 16);
            }
        }
        __syncthreads();

        const int q0base = z * 192 + w * 48;
        bf16x8 qfrag[3];
        bool qin[3];
        int qpix[3];
#pragma unroll
        for (int qt = 0; qt < 3; qt++) {
            int qa = q0base + qt * 16 + qloc;
            int gr = wi * WSZ - PADK + qa / OWSZ, gc = wj * WSZ - PADK + qa % OWSZ;
            bool ib = (gr >= 0 && gr < HH && gc >= 0 && gc < WW);
            qin[qt] = ib;
            qpix[qt] = ib ? gr * WW + gc : 0;
            B8 f;
#pragma unroll
            for (int j = 0; j < 4; j++) f.u[j] = 0;
            if (ib && g < 2)
                f.v = *(const bf16x8*)(qkvu + (size_t)qpix[qt] * 192 + 32 + 8 * h + 4 * g);
            qfrag[qt] = f.v;
        }

        f32x4 O[3];
        float lsum[3];
#pragma unroll
        for (int qt = 0; qt < 3; qt++) { O[qt] = zz; lsum[qt] = 0.f; }

        f32x4 cA[3], cB[3];
#pragma unroll
        for (int qt = 0; qt < 3; qt++) {
            int qa = q0base + qt * 16 + qloc;
            const float* bp = bias2T + ((size_t)h * NQ1 + 4 * g) * NKV1 + qa;
#pragma unroll
            for (int r = 0; r < 4; r++) {
                cA[qt][r] = bp[(size_t)r * NKV1];
                cB[qt][r] = bp[(size_t)(16 + r) * NKV1];
            }
        }

        for (int step = 0; step < 8; step++) {
            const int k0 = step * 32;
            bf16x8 kfA, kfB;
            if (g < 2) {
                kfA = *(const bf16x8*)&K_lds[k0 + qloc][4 * g];
                kfB = *(const bf16x8*)&K_lds[k0 + 16 + qloc][4 * g];
            } else {
                B8 zf;
#pragma unroll
                for (int j = 0; j < 4; j++) zf.u[j] = 0;
                kfA = zf.v; kfB = zf.v;
            }
            bf16x8 vfv = *(const bf16x8*)&Vt[step][lane][0];

            f32x4 nA[3], nB[3];
            if (step < 7) {
#pragma unroll
                for (int qt = 0; qt < 3; qt++) {
                    int qa = q0base + qt * 16 + qloc;
                    const float* bp = bias2T + ((size_t)h * NQ1 + k0 + 32 + 4 * g) * NKV1 + qa;
#pragma unroll
                    for (int r = 0; r < 4; r++) {
                        nA[qt][r] = bp[(size_t)r * NKV1];
                        nB[qt][r] = bp[(size_t)(16 + r) * NKV1];
                    }
                }
            }

#pragma unroll
            for (int qt = 0; qt < 3; qt++) {
                f32x4 sA = __builtin_amdgcn_mfma_f32_16x16x32_bf16(kfA, qfrag[qt], cA[qt], 0, 0, 0);
                f32x4 sB = __builtin_amdgcn_mfma_f32_16x16x32_bf16(kfB, qfrag[qt], cB[qt], 0, 0, 0);
                float pa[4], pb[4];
                float ls = 0.f;
#pragma unroll
                for (int r = 0; r < 4; r++) {
                    pa[r] = exp2f(sA[r]);
                    pb[r] = exp2f(sB[r]);
                    ls += pa[r] + pb[r];
                }
                B8 pf;
                pf.u[0] = cvtpk(pa[0], pa[1]);
                pf.u[1] = cvtpk(pa[2], pa[3]);
                pf.u[2] = cvtpk(pb[0], pb[1]);
                pf.u[3] = cvtpk(pb[2], pb[3]);
                lsum[qt] += ls;
                O[qt] = __builtin_amdgcn_mfma_f32_16x16x32_bf16(vfv, pf.v, O[qt], 0, 0, 0);
            }
            if (step < 7) {
#pragma unroll
                for (int qt = 0; qt < 3; qt++) { cA[qt] = nA[qt]; cB[qt] = nB[qt]; }
            }
        }

#pragma unroll
        for (int qt = 0; qt < 3; qt++) {
            float lt = lsum[qt];
            lt += __shfl_xor(lt, 16);
            lt += __shfl_xor(lt, 32);
            float rl = 1.f / lt;
            int qa = q0base + qt * 16 + qloc;
            size_t obase = ((size_t)win * NKV1 + qa) * C2K + h * HD + 4 * g;
            size_t rbase = (size_t)qpix[qt] * 128 + C2K + h * HD + 4 * g;
#pragma unroll
            for (int r = 0; r < 4; r++)
                bb[obase + r] = O[qt][r] * rl + (qin[qt] ? lnx[rbase + r] : 0.f);
        }
    }
}

// ---------------- fold (gather form, no atomics) ----------------
__global__ void fold_kernel(const float* __restrict__ bb, float* __restrict__ folded)
{
    int idx = blockIdx.x * 256 + threadIdx.x;
    if (idx >= 200 * 200 * 64) return;
    int c = idx & 63;
    int j = (idx >> 6) % 200;
    int i = idx / (64 * 200);
    int ilo = (i > 23) ? ((i - 8) >> 4) : 0;
    int ihi = min(11, i >> 4);
    int jlo = (j > 23) ? ((j - 8) >> 4) : 0;
    int jhi = min(11, j >> 4);
    float s = 0.f;
    for (int wi = ilo; wi <= ihi; wi++)
        for (int wj = jlo; wj <= jhi; wj++) {
            int p = (i - wi * 16) * OWSZ + (j - wj * 16);
            s += bb[((size_t)(wi * NWIN + wj) * NKV1 + p) * C2K + c];
        }
    folded[idx] = s;
}

// ---------------- bicubic resize 200->192 ----------------
__device__ __forceinline__ float cubicw(float x)
{
    float ax = fabsf(x);
    const float A = -0.75f;
    if (ax <= 1.f) return ((A + 2.f) * ax - (A + 3.f)) * ax * ax + 1.f;
    if (ax < 2.f)  return A * (ax * (ax * (ax - 5.f) + 8.f) - 4.f);
    return 0.f;
}

__global__ void resize_kernel(const float* __restrict__ folded, float* __restrict__ xcat)
{
    int idx = blockIdx.x * 256 + threadIdx.x;
    if (idx >= HH * WW * C2K) return;
    int c = idx & 63;
    int p = (idx >> 6) % WW;
    int o = idx / (C2K * WW);
    const float ratio = 200.f / 192.f;
    float sr = (o + 0.5f) * ratio - 0.5f;
    float sc = (p + 0.5f) * ratio - 0.5f;
    int fr = (int)floorf(sr), fcc = (int)floorf(sc);
    float wc[4]; int ic[4];
#pragma unroll
    for (int u = 0; u < 4; u++) {
        int jj = fcc - 1 + u;
        wc[u] = cubicw(sc - (float)jj);
        ic[u] = min(max(jj, 0), 199);
    }
    float acc = 0.f;
#pragma unroll
    for (int t = 0; t < 4; t++) {
        int ii = fr - 1 + t;
        float wr = cubicw(sr - (float)ii);
        int ir = min(max(ii, 0), 199);
        const float* rowp = folded + ((size_t)ir * 200) * 64 + c;
        float rs = 0.f;
#pragma unroll
        for (int u = 0; u < 4; u++) rs += wc[u] * rowp[(size_t)ic[u] * 64];
        acc += wr * rs;
    }
    xcat[(size_t)(o * WW + p) * 128 + C2K + c] = acc;
}

// ---------------- proj GEMM + residual + fused LN2 -> x_buf(f32) and y(bf16) ----------------
__launch_bounds__(256)
__global__ void proj_ln2(const float* __restrict__ A1,
                         const bf16* __restrict__ WT,
                         const float* __restrict__ bias,
                         const float* __restrict__ R,
                         const float* __restrict__ ln2w, const float* __restrict__ ln2b,
                         float* __restrict__ xbuf, unsigned* __restrict__ ybf)
{
    __shared__ float psum[16][16];
    __shared__ float psq[16][16];
    __shared__ float mu_s[16], inv_s[16];

    const int tid = threadIdx.x;
    const int lane = tid & 63, w = tid >> 6;
    const int g = lane >> 4, nl = lane & 15;

    bf16x8 wf[2][4];
#pragma unroll
    for (int t = 0; t < 2; t++) {
        const bf16* wp = WT + (size_t)((w * 2 + t) * 16 + nl) * 128;
#pragma unroll
        for (int ks = 0; ks < 4; ks++)
            wf[t][ks] = *(const bf16x8*)(wp + ks * 32 + 8 * g);
    }

    const int row = (blockIdx.x * 4 + blockIdx.y) * 16 + nl;
    bf16x8 xf[4];
    const float* ap = A1 + (size_t)row * 128 + 8 * g;
#pragma unroll
    for (int ks = 0; ks < 4; ks++) {
        float4 v0 = *(const float4*)(ap + ks * 32);
        float4 v1 = *(const float4*)(ap + ks * 32 + 4);
        B8 f;
        f.u[0] = cvtpk(v0.x, v0.y);
        f.u[1] = cvtpk(v0.z, v0.w);
        f.u[2] = cvtpk(v1.x, v1.y);
        f.u[3] = cvtpk(v1.z, v1.w);
        xf[ks] = f.v;
    }

    const f32x4 zz = {0.f, 0.f, 0.f, 0.f};
    f32x4 acc[2];
    acc[0] = zz; acc[1] = zz;
#pragma unroll
    for (int ks = 0; ks < 4; ks++) {
        acc[0] = __builtin_amdgcn_mfma_f32_16x16x32_bf16(wf[0][ks], xf[ks], acc[0], 0, 0, 0);
        acc[1] = __builtin_amdgcn_mfma_f32_16x16x32_bf16(wf[1][ks], xf[ks], acc[1], 0, 0, 0);
    }

    float o[2][4];
    float s = 0.f, sq = 0.f;
#pragma unroll
    for (int t = 0; t < 2; t++) {
        int n0t = (w * 2 + t) * 16 + 4 * g;
        float4 bv = *(const float4*)(bias + n0t);
        float4 rv = *(const float4*)(R + (size_t)row * 128 + n0t);
        o[t][0] = acc[t][0] + bv.x + rv.x;
        o[t][1] = acc[t][1] + bv.y + rv.y;
        o[t][2] = acc[t][2] + bv.z + rv.z;
        o[t][3] = acc[t][3] + bv.w + rv.w;
#pragma unroll
        for (int r = 0; r < 4; r++) { s += o[t][r]; sq += o[t][r] * o[t][r]; }
    }
    psum[nl][w * 4 + g] = s;
    psq[nl][w * 4 + g] = sq;
    __syncthreads();
    if (tid < 16) {
        float ts = 0.f, tq = 0.f;
#pragma unroll
        for (int i = 0; i < 16; i++) { ts += psum[tid][i]; tq += psq[tid][i]; }
        float mu = ts * 0.0078125f;
        float var = fmaxf(tq * 0.0078125f - mu * mu, 0.f);
        mu_s[tid] = mu;
        inv_s[tid] = 1.0f / sqrtf(var + 1e-5f);
    }
    __syncthreads();

    float mu = mu_s[nl], inv = inv_s[nl];
#pragma unroll
    for (int t = 0; t < 2; t++) {
        int n0t = (w * 2 + t) * 16 + 4 * g;
        *(float4*)(xbuf + (size_t)row * 128 + n0t) = make_float4(o[t][0], o[t][1], o[t][2], o[t][3]);
        float4 gw = *(const float4*)(ln2w + n0t);
        float4 gb = *(const float4*)(ln2b + n0t);
        float y0 = (o[t][0] - mu) * inv * gw.x + gb.x;
        float y1 = (o[t][1] - mu) * inv * gw.y + gb.y;
        float y2 = (o[t][2] - mu) * inv * gw.z + gb.z;
        float y3 = (o[t][3] - mu) * inv * gw.w + gb.w;
        uint2 yo;
        yo.x = cvtpk(y0, y1);
        yo.y = cvtpk(y2, y3);
        *(uint2*)(ybf + (size_t)row * 64 + (n0t >> 1)) = yo;
    }
}

// ---------------- fc1 GEMM (A bf16) + fused sgn-LN -> x1b (bf16) | x2b (LN'd bf16) ----------------
__launch_bounds__(256)
__global__ void fc1_sgn(const unsigned* __restrict__ ybf,
                        const bf16* __restrict__ WT,
                        const float* __restrict__ bias,
                        const float* __restrict__ sgnw, const float* __restrict__ sgnb,
                        unsigned* __restrict__ x1b, unsigned* __restrict__ x2b)
{
    __shared__ float psum[16][8];
    __shared__ float psq[16][8];
    __shared__ float mu_s[16], inv_s[16];

    const int tid = threadIdx.x;
    const int lane = tid & 63, w = tid >> 6;
    const int g = lane >> 4, nl = lane & 15;

    bf16x8 wf[4][4];
#pragma unroll
    for (int t = 0; t < 4; t++) {
        const bf16* wp = WT + (size_t)((w * 4 + t) * 16 + nl) * 128;
#pragma unroll
        for (int ks = 0; ks < 4; ks++)
            wf[t][ks] = *(const bf16x8*)(wp + ks * 32 + 8 * g);
    }

    const int row = (blockIdx.x * 4 + blockIdx.y) * 16 + nl;
    bf16x8 xf[4];
    const unsigned* ap = ybf + (size_t)row * 64 + 4 * g;
#pragma unroll
    for (int ks = 0; ks < 4; ks++)
        xf[ks] = *(const bf16x8*)(ap + ks * 16);

    const f32x4 zz = {0.f, 0.f, 0.f, 0.f};
    f32x4 acc[4];
#pragma unroll
    for (int t = 0; t < 4; t++) acc[t] = zz;
#pragma unroll
    for (int ks = 0; ks < 4; ks++)
#pragma unroll
        for (int t = 0; t < 4; t++)
            acc[t] = __builtin_amdgcn_mfma_f32_16x16x32_bf16(wf[t][ks], xf[ks], acc[t], 0, 0, 0);

    float o[4][4];
    float s = 0.f, sq = 0.f;
#pragma unroll
    for (int t = 0; t < 4; t++) {
        int n0t = (w * 4 + t) * 16 + 4 * g;
        float4 bv = *(const float4*)(bias + n0t);
        o[t][0] = acc[t][0] + bv.x;
        o[t][1] = acc[t][1] + bv.y;
        o[t][2] = acc[t][2] + bv.z;
        o[t][3] = acc[t][3] + bv.w;
    }
    if (w >= 2) {
#pragma unroll
        for (int t = 0; t < 4; t++)
#pragma unroll
            for (int r = 0; r < 4; r++) { s += o[t][r]; sq += o[t][r] * o[t][r]; }
        psum[nl][(w - 2) * 4 + g] = s;
        psq[nl][(w - 2) * 4 + g] = sq;
    }
    __syncthreads();
    if (tid < 16) {
        float ts = 0.f, tq = 0.f;
#pragma unroll
        for (int i = 0; i < 8; i++) { ts += psum[tid][i]; tq += psq[tid][i]; }
        float mu = ts * 0.0078125f;
        float var = fmaxf(tq * 0.0078125f - mu * mu, 0.f);
        mu_s[tid] = mu;
        inv_s[tid] = 1.0f / sqrtf(var + 1e-5f);
    }
    __syncthreads();

    if (w < 2) {
#pragma unroll
        for (int t = 0; t < 4; t++) {
            int n0t = (w * 4 + t) * 16 + 4 * g;   // 0..127
            uint2 xo;
            xo.x = cvtpk(o[t][0], o[t][1]);
            xo.y = cvtpk(o[t][2], o[t][3]);
            *(uint2*)(x1b + (size_t)row * 64 + (n0t >> 1)) = xo;
        }
    } else {
        float mu = mu_s[nl], inv = inv_s[nl];
#pragma unroll
        for (int t = 0; t < 4; t++) {
            int n0t = (w * 4 + t) * 16 + 4 * g;
            int m0t = n0t - 128;                  // 0..127
            float4 gw = *(const float4*)(sgnw + m0t);
            float4 gb = *(const float4*)(sgnb + m0t);
            float y0 = (o[t][0] - mu) * inv * gw.x + gb.x;
            float y1 = (o[t][1] - mu) * inv * gw.y + gb.y;
            float y2 = (o[t][2] - mu) * inv * gw.z + gb.z;
            float y3 = (o[t][3] - mu) * inv * gw.w + gb.w;
            uint2 xo;
            xo.x = cvtpk(y0, y1);
            xo.y = cvtpk(y2, y3);
            *(uint2*)(x2b + (size_t)row * 64 + (m0t >> 1)) = xo;
        }
    }
}

// ---------------- depthwise 3x3 conv on bf16 x2, fused x1 multiply -> ab (bf16) ----------------
// round-12/15 scalar form (proven)
__global__ void dwconv_kernel(const unsigned short* __restrict__ x2b,
                              const unsigned short* __restrict__ x1b,
                              const float* __restrict__ conv_w,
                              const float* __restrict__ conv_b,
                              unsigned short* __restrict__ ab)
{
    int idx = blockIdx.x * 256 + threadIdx.x;
    if (idx >= NTOK * 128) return;
    int ch = idx & 127, t = idx >> 7;
    int i = t / WW, j = t % WW;
    float acc = conv_b[ch];
#pragma unroll
    for (int a = 0; a < 3; a++) {
        int ii = i + a - 1;
        if (ii < 0 || ii >= HH) continue;
#pragma unroll
        for (int b = 0; b < 3; b++) {
            int jj = j + b - 1;
            if (jj < 0 || jj >= WW) continue;
            acc += conv_w[ch * 9 + a * 3 + b] * bfu2f(x2b[(size_t)(ii * WW + jj) * 128 + ch]);
        }
    }
    float prod = bfu2f(x1b[(size_t)t * 128 + ch]) * acc;
    unsigned u = __float_as_uint(prod);
    ab[(size_t)t * 128 + ch] = (unsigned short)((u + 0x7FFFu + ((u >> 16) & 1u)) >> 16);
}

// ---------------- fc2 GEMM (A bf16 direct) + bias + residual -> out f32, N=128 ----------------
__launch_bounds__(256)
__global__ void gemm_bfA(const unsigned* __restrict__ Au,
                         const bf16* __restrict__ WT,
                         const float* __restrict__ bias,
                         const float* __restrict__ R,
                         float* __restrict__ C)
{
    const int tid = threadIdx.x;
    const int lane = tid & 63, w = tid >> 6;
    const int g = lane >> 4, nl = lane & 15;

    bf16x8 wf[2][4];
#pragma unroll
    for (int t = 0; t < 2; t++) {
        const bf16* wp = WT + (size_t)((w * 2 + t) * 16 + nl) * 128;
#pragma unroll
        for (int ks = 0; ks < 4; ks++)
            wf[t][ks] = *(const bf16x8*)(wp + ks * 32 + 8 * g);
    }

    const int row = (blockIdx.x * 4 + blockIdx.y) * 16 + nl;
    bf16x8 xf[4];
    const unsigned* ap = Au + (size_t)row * 64 + 4 * g;
#pragma unroll
    for (int ks = 0; ks < 4; ks++)
        xf[ks] = *(const bf16x8*)(ap + ks * 16);

    const f32x4 zz = {0.f, 0.f, 0.f, 0.f};
    f32x4 acc[2];
    acc[0] = zz; acc[1] = zz;
#pragma unroll
    for (int ks = 0; ks < 4; ks++) {
        acc[0] = __builtin_amdgcn_mfma_f32_16x16x32_bf16(wf[0][ks], xf[ks], acc[0], 0, 0, 0);
        acc[1] = __builtin_amdgcn_mfma_f32_16x16x32_bf16(wf[1][ks], xf[ks], acc[1], 0, 0, 0);
    }

#pragma unroll
    for (int t = 0; t < 2; t++) {
        const int n0t = (w * 2 + t) * 16 + 4 * g;
        float4 bv = *(const float4*)(bias + n0t);
        float4 rv = *(const float4*)(R + (size_t)row * 128 + n0t);
        float4 o;
        o.x = acc[t][0] + bv.x + rv.x;
        o.y = acc[t][1] + bv.y + rv.y;
        o.z = acc[t][2] + bv.z + rv.z;
        o.w = acc[t][3] + bv.w + rv.w;
        *(float4*)(C + (size_t)row * 128 + n0t) = o;
    }
}

extern "C" void kernel_launch(void* const* d_in, const int* in_sizes, int n_in,
                              void* d_out, int out_size, void* d_ws, size_t ws_size,
                              hipStream_t stream)
{
    (void)in_sizes; (void)n_in; (void)out_size; (void)ws_size;
    const float* x_tkn  = (const float*)d_in[0];
    const float* ln1_w  = (const float*)d_in[1];
    const float* ln1_b  = (const float*)d_in[2];
    const float* q1_w   = (const float*)d_in[3];
    const float* kv1_w  = (const float*)d_in[4];
    const float* rpb1   = (const float*)d_in[5];
    const float* q2_w   = (const float*)d_in[6];
    const float* kv2_w  = (const float*)d_in[7];
    const float* rpb2   = (const float*)d_in[8];
    const float* proj_w = (const float*)d_in[9];
    const float* proj_b = (const float*)d_in[10];
    const float* ln2_w  = (const float*)d_in[11];
    const float* ln2_b  = (const float*)d_in[12];
    const float* fc1_w  = (const float*)d_in[13];
    const float* fc1_b  = (const float*)d_in[14];
    const float* sgn_w  = (const float*)d_in[15];
    const float* sgn_b  = (const float*)d_in[16];
    const float* conv_w = (const float*)d_in[17];
    const float* conv_b = (const float*)d_in[18];
    const float* fc2_w  = (const float*)d_in[19];
    const float* fc2_b  = (const float*)d_in[20];
    const int*   rpi    = (const int*)d_in[21];

    float* ws = (float*)d_ws;
    // layout (float units); ordered-alias verified (same as rounds 12-16):
    float* lnx    = ws;                      // 0 .. 4,718,592    (LN1 out; later x_buf)
    float* xcat   = ws + 4718592;            // .. 9,437,184      (x_cat)
    float* bbuf   = ws + 9437184;            // .. 14,745,600     (bb; later ybf)
    bf16*  projT  = (bf16*)(ws + 14155776);  // bb tail, written AFTER fold
    bf16*  fc1T   = (bf16*)(ws + 14163968);
    bf16*  fc2T   = (bf16*)(ws + 14180352);
    float* bias1T = ws + 14745600;           // .. 15,335,424 (dead after attn)
    float* bias2T = ws + 17104896;           // .. 17,694,720 (dead after attn)
    float* qkv    = ws + 17694720;           // .. 24,772,608 (192 uints/row; dead after attn)
    bf16*  wcombT = (bf16*)(ws + 24772608);  // .. 24,797,184 (dead after qkv gemm)
    float* foldp  = ws + 17694720;           // aliases qkv (dead after resize)
    unsigned* ybf = (unsigned*)bbuf;         // bb dead after fold
    unsigned* x1b = (unsigned*)(ws + 14745600);  // .. 17,104,896
    unsigned* x2b = (unsigned*)(ws + 17104896);  // .. 19,464,192
    unsigned* ab  = (unsigned*)(ws + 19464192);  // .. 21,823,488
    float* out    = (float*)d_out;

    // 1. weight + bias prep
    wcombT_kernel<<<(384 * 128) / 256, 256, 0, stream>>>(q1_w, kv1_w, q2_w, kv2_w, wcombT);
    bias1_kernel<<<(H2K * NKV1 * NQ1) / 256, 256, 0, stream>>>(rpb1, rpi, bias1T);
    bias2_kernel<<<(H2K * NQ1 * NKV1) / 256, 256, 0, stream>>>(rpb2, rpi, bias2T);
    // 2. qkv = LN1(x_tkn) @ Wcomb (N=384) -> bf16; also writes lnx f32
    gemm_qkv<<<dim3(NTOK / 64, 4), 256, 0, stream>>>(x_tkn, ln1_w, ln1_b, wcombT,
                                                     (unsigned*)qkv, lnx);
    // 3. fused attention (attn1 + attn2, V transposed, bias as prefetched MFMA C)
    attn_fused<<<dim3(720, 4), 256, 0, stream>>>((const unsigned*)qkv, lnx,
                                                 bias1T, bias2T, xcat, bbuf);
    // 4. fold bb -> folded (200x200x64)
    fold_kernel<<<(200 * 200 * 64) / 256, 256, 0, stream>>>(bbuf, foldp);
    // 4b. transpose fc weights into bb tail (bb dead)
    wtrans_kernel<<<(128 * 128) / 256, 256, 0, stream>>>(proj_w, 128, projT);
    wtrans_kernel<<<(256 * 128) / 256, 256, 0, stream>>>(fc1_w, 256, fc1T);
    wtrans_kernel<<<(128 * 128) / 256, 256, 0, stream>>>(fc2_w, 128, fc2T);
    // 5. bicubic resize -> xcat[:, 64:128]
    resize_kernel<<<(HH * WW * C2K) / 256, 256, 0, stream>>>(foldp, xcat);
    // 6. proj + residual + fused LN2: x_buf(lnx, f32) and y(ybf, bf16)
    proj_ln2<<<dim3(NTOK / 64, 4), 256, 0, stream>>>(xcat, projT, proj_b, x_tkn,
                                                     ln2_w, ln2_b, lnx, ybf);
    // 7. fc1 + fused sgn-LN -> x1b, x2b (compact bf16)
    fc1_sgn<<<dim3(NTOK / 64, 4), 256, 0, stream>>>(ybf, fc1T, fc1_b, sgn_w, sgn_b, x1b, x2b);
    // 8. depthwise conv + x1 multiply -> ab (bf16), scalar proven form
    dwconv_kernel<<<(NTOK * 128) / 256, 256, 0, stream>>>((const unsigned short*)x2b,
                                                          (const unsigned short*)x1b,
                                                          conv_w, conv_b,
                                                          (unsigned short*)ab);
    // 9. fc2: out = ab @ fc2_w + fc2_b + x_buf
    gemm_bfA<<<dim3(NTOK / 64, 4), 256, 0, stream>>>(ab, fc2T, fc2_b, lnx, out);
}

// Round 18
// 272.080 us; speedup vs baseline: 1.0319x; 1.0049x over previous
//
#include <hip/hip_runtime.h>
#include <hip/hip_bf16.h>

#define HH 192
#define WW 192
#define NWIN 12
#define WSZ 16
#define OWSZ 24
#define PADK 4
#define NQ1 256      // WS*WS
#define NKV1 576     // OWS*OWS
#define C2K 64
#define H2K 4
#define HD 16        // head dim
#define NTOK (HH*WW)
#define LOG2E 1.4426950408889634f
#define QSCALE (0.25f * LOG2E)

typedef __hip_bfloat16 bf16;
typedef __attribute__((ext_vector_type(8))) short bf16x8;
typedef __attribute__((ext_vector_type(4))) float f32x4;

union B8 { short s[8]; bf16x8 v; unsigned u[4]; };

__device__ __forceinline__ unsigned cvtpk(float lo, float hi)
{
    unsigned r;
    asm("v_cvt_pk_bf16_f32 %0, %1, %2" : "=v"(r) : "v"(lo), "v"(hi));
    return r;
}
__device__ __forceinline__ float bfu2f(unsigned short u)
{
    return __uint_as_float(((unsigned)u) << 16);
}

// ---------------- combined projection weight, transposed bf16, PERMUTED columns ----------------
__global__ void wcombT_kernel(const float* __restrict__ q1_w, const float* __restrict__ kv1_w,
                              const float* __restrict__ q2_w, const float* __restrict__ kv2_w,
                              bf16* __restrict__ WT)
{
    int idx = blockIdx.x * 256 + threadIdx.x;
    if (idx >= 384 * 128) return;
    int cp = idx >> 7, r = idx & 127;
    int c;   // original semantic column
    if (cp < 64) c = cp;
    else if (cp < 128) c = 192 + (cp - 64);
    else if (cp < 256) {
        int j = cp - 128, h = j >> 5, m = j & 31;
        c = (m < 16) ? (64 + 16 * h + m) : (128 + 16 * h + (m - 16));
    } else {
        int j = cp - 256, h = j >> 5, m = j & 31;
        c = (m < 16) ? (256 + 16 * h + m) : (320 + 16 * h + (m - 16));
    }
    float v = 0.f;
    if (c < 64)       { if (r < 64)  v = q1_w[r * 64 + c] * QSCALE; }
    else if (c < 192) { if (r >= 64) v = kv1_w[(r - 64) * 128 + (c - 64)]; }
    else if (c < 256) { if (r >= 64) v = q2_w[(r - 64) * 64 + (c - 192)] * QSCALE; }
    else              { if (r < 64)  v = kv2_w[r * 128 + (c - 256)]; }
    WT[idx] = __float2bfloat16(v);
}

// ---------------- generic weight transpose to bf16: dst[n][k] = src[k][n], K=128 ----------------
__global__ void wtrans_kernel(const float* __restrict__ src, int N, bf16* __restrict__ dst)
{
    int idx = blockIdx.x * 256 + threadIdx.x;
    if (idx >= N * 128) return;
    int n = idx >> 7, k = idx & 127;
    dst[idx] = __float2bfloat16(src[(size_t)k * N + n]);
}

// ---------------- bias transposes (pre-scaled by log2(e)) ----------------
__global__ void bias1_kernel(const float* __restrict__ rpb1, const int* __restrict__ rpi,
                             float* __restrict__ biasT)   // [h][n][q]
{
    int idx = blockIdx.x * 256 + threadIdx.x;
    if (idx >= H2K * NKV1 * NQ1) return;
    int q = idx & 255;
    int n = (idx >> 8) % NKV1;
    int h = idx / (NKV1 * NQ1);
    biasT[idx] = rpb1[rpi[q * NKV1 + n] * H2K + h] * LOG2E;
}

__global__ void bias2_kernel(const float* __restrict__ rpb2, const int* __restrict__ rpi,
                             float* __restrict__ biasT)   // [h][k][q]
{
    int idx = blockIdx.x * 256 + threadIdx.x;
    if (idx >= H2K * NQ1 * NKV1) return;
    int q = idx % NKV1;
    int k = (idx / NKV1) % NQ1;
    int h = idx / (NKV1 * NQ1);
    biasT[idx] = rpb2[rpi[k * NKV1 + q] * H2K + h] * LOG2E;
}

// ---------------- qkv GEMM (N=384) with fused LN1 -> qkv bf16 (192-uint rows) + lnx f32 ----------------
__launch_bounds__(256)
__global__ void gemm_qkv(const float* __restrict__ x_tkn,
                         const float* __restrict__ ln1w, const float* __restrict__ ln1b,
                         const bf16* __restrict__ WT,
                         unsigned* __restrict__ qkvo, float* __restrict__ lnx)
{
    const int tid = threadIdx.x;
    const int lane = tid & 63, w = tid >> 6;
    const int g = lane >> 4, nl = lane & 15;

    bf16x8 wf[6][4];
#pragma unroll
    for (int t = 0; t < 6; t++) {
        const bf16* wp = WT + (size_t)((w * 6 + t) * 16 + nl) * 128;
#pragma unroll
        for (int ks = 0; ks < 4; ks++)
            wf[t][ks] = *(const bf16x8*)(wp + ks * 32 + 8 * g);
    }

    const int row = (blockIdx.x * 4 + blockIdx.y) * 16 + nl;
    const float* ap = x_tkn + (size_t)row * 128 + 8 * g;

    float av[4][8];
    float s = 0.f, sq = 0.f;
#pragma unroll
    for (int ks = 0; ks < 4; ks++) {
        float4 v0 = *(const float4*)(ap + ks * 32);
        float4 v1 = *(const float4*)(ap + ks * 32 + 4);
        av[ks][0] = v0.x; av[ks][1] = v0.y; av[ks][2] = v0.z; av[ks][3] = v0.w;
        av[ks][4] = v1.x; av[ks][5] = v1.y; av[ks][6] = v1.z; av[ks][7] = v1.w;
#pragma unroll
        for (int j = 0; j < 8; j++) { s += av[ks][j]; sq += av[ks][j] * av[ks][j]; }
    }
    s  += __shfl_xor(s, 16);  s  += __shfl_xor(s, 32);
    sq += __shfl_xor(sq, 16); sq += __shfl_xor(sq, 32);
    float mu  = s * 0.0078125f;
    float var = fmaxf(sq * 0.0078125f - mu * mu, 0.f);
    float inv = 1.0f / sqrtf(var + 1e-5f);

    bf16x8 xf[4];
#pragma unroll
    for (int ks = 0; ks < 4; ks++) {
        int col = ks * 32 + 8 * g;
        float4 g0 = *(const float4*)(ln1w + col);
        float4 g1 = *(const float4*)(ln1w + col + 4);
        float4 b0 = *(const float4*)(ln1b + col);
        float4 b1 = *(const float4*)(ln1b + col + 4);
        float nv[8];
        nv[0] = (av[ks][0] - mu) * inv * g0.x + b0.x;
        nv[1] = (av[ks][1] - mu) * inv * g0.y + b0.y;
        nv[2] = (av[ks][2] - mu) * inv * g0.z + b0.z;
        nv[3] = (av[ks][3] - mu) * inv * g0.w + b0.w;
        nv[4] = (av[ks][4] - mu) * inv * g1.x + b1.x;
        nv[5] = (av[ks][5] - mu) * inv * g1.y + b1.y;
        nv[6] = (av[ks][6] - mu) * inv * g1.z + b1.z;
        nv[7] = (av[ks][7] - mu) * inv * g1.w + b1.w;
        if (w == 0) {
            float* lp = lnx + (size_t)row * 128 + col;
            *(float4*)lp       = make_float4(nv[0], nv[1], nv[2], nv[3]);
            *(float4*)(lp + 4) = make_float4(nv[4], nv[5], nv[6], nv[7]);
        }
        B8 f;
        f.u[0] = cvtpk(nv[0], nv[1]);
        f.u[1] = cvtpk(nv[2], nv[3]);
        f.u[2] = cvtpk(nv[4], nv[5]);
        f.u[3] = cvtpk(nv[6], nv[7]);
        xf[ks] = f.v;
    }

    const f32x4 zz = {0.f, 0.f, 0.f, 0.f};
    f32x4 acc[6];
#pragma unroll
    for (int t = 0; t < 6; t++) acc[t] = zz;
#pragma unroll
    for (int ks = 0; ks < 4; ks++)
#pragma unroll
        for (int t = 0; t < 6; t++)
            acc[t] = __builtin_amdgcn_mfma_f32_16x16x32_bf16(wf[t][ks], xf[ks], acc[t], 0, 0, 0);

#pragma unroll
    for (int t = 0; t < 6; t++) {
        int n0t = (w * 6 + t) * 16 + 4 * g;
        uint2 o;
        o.x = cvtpk(acc[t][0], acc[t][1]);
        o.y = cvtpk(acc[t][2], acc[t][3]);
        *(uint2*)(qkvo + (size_t)row * 192 + (n0t >> 1)) = o;
    }
}

// ---------------- fused attention. grid (720, 4). K swizzled 32B rows; V transposed; bias prefetched C ----------------
// K_lds row n: physical 16B slot = logical ^ ((n>>2)&1)  (2-way banks = free)
__launch_bounds__(256)
__global__ void attn_fused(const unsigned* __restrict__ qkvu,
                           const float* __restrict__ lnx,
                           const float* __restrict__ bias1T,   // [h][n][q]
                           const float* __restrict__ bias2T,   // [h][k][q]
                           float* __restrict__ xcat,
                           float* __restrict__ bb)
{
    __shared__ unsigned K_lds[NKV1][8];
    __shared__ unsigned short Vt[18][64][8];

    const int h = blockIdx.y;
    const int tid = threadIdx.x;
    const int lane = tid & 63, w = tid >> 6;
    const int g = lane >> 4, qloc = lane & 15;
    const int sw = (qloc >> 2) & 1;             // K read-slot swizzle (step-independent)
    const f32x4 zz = {0.f, 0.f, 0.f, 0.f};

    if (blockIdx.x < 288) {
        // ---------------- attn1: 256 window q x 576 patch keys ----------------
        const int win = blockIdx.x % 144, z = blockIdx.x / 144;
        const int wi = win / NWIN, wj = win % NWIN;

        for (int n = tid; n < NKV1; n += 256) {
            int rr = wi * WSZ - PADK + n / OWSZ, cc = wj * WSZ - PADK + n % OWSZ;
            bool ib = (rr >= 0 && rr < HH && cc >= 0 && cc < WW);
            uint4 k0v = make_uint4(0, 0, 0, 0), k1v = k0v, v0v = k0v, v1v = k0v;
            if (ib) {
                const unsigned* src = qkvu + (size_t)(rr * WW + cc) * 192 + 64 + 16 * h;
                k0v = *(const uint4*)(src);
                k1v = *(const uint4*)(src + 4);
                v0v = *(const uint4*)(src + 8);
                v1v = *(const uint4*)(src + 12);
            }
            int sn = (n >> 2) & 1;
            *(uint4*)&K_lds[n][4 * sn]       = k0v;
            *(uint4*)&K_lds[n][4 * (1 - sn)] = k1v;
            int step = n >> 5, ko = n & 31;
            int gq = (ko & 15) >> 2;
            int j = (ko & 3) | ((ko >> 4) << 2);
            unsigned vv[8] = {v0v.x, v0v.y, v0v.z, v0v.w, v1v.x, v1v.y, v1v.z, v1v.w};
            unsigned short* vt = &Vt[step][gq * 16][j];
#pragma unroll
            for (int d = 0; d < 8; d++) {
                vt[(2 * d) * 8]     = (unsigned short)(vv[d] & 0xffff);
                vt[(2 * d + 1) * 8] = (unsigned short)(vv[d] >> 16);
            }
        }
        __syncthreads();

        const int q0base = z * 128 + w * 32;
        bf16x8 qfrag[2];
#pragma unroll
        for (int qt = 0; qt < 2; qt++) {
            int q = q0base + qt * 16 + qloc;
            int pix = (wi * WSZ + (q >> 4)) * WW + wj * WSZ + (q & 15);
            B8 f;
#pragma unroll
            for (int j = 0; j < 4; j++) f.u[j] = 0;
            if (g < 2)
                f.v = *(const bf16x8*)(qkvu + (size_t)pix * 192 + 8 * h + 4 * g);
            qfrag[qt] = f.v;
        }

        f32x4 O[2];
        float lsum[2];
#pragma unroll
        for (int qt = 0; qt < 2; qt++) { O[qt] = zz; lsum[qt] = 0.f; }

        // bias prefetch: load step 0
        f32x4 cA[2], cB[2];
#pragma unroll
        for (int qt = 0; qt < 2; qt++) {
            int qa = q0base + qt * 16 + qloc;
            const float* bp = bias1T + ((size_t)h * NKV1 + 4 * g) * NQ1 + qa;
#pragma unroll
            for (int r = 0; r < 4; r++) {
                cA[qt][r] = bp[(size_t)r * NQ1];
                cB[qt][r] = bp[(size_t)(16 + r) * NQ1];
            }
        }

        for (int step = 0; step < 18; step++) {
            const int k0 = step * 32;
            bf16x8 kfA, kfB;
            if (g < 2) {
                int gs = 4 * (g ^ sw);
                kfA = *(const bf16x8*)&K_lds[k0 + qloc][gs];
                kfB = *(const bf16x8*)&K_lds[k0 + 16 + qloc][gs];
            } else {
                B8 zf;
#pragma unroll
                for (int j = 0; j < 4; j++) zf.u[j] = 0;
                kfA = zf.v; kfB = zf.v;
            }
            bf16x8 vfv = *(const bf16x8*)&Vt[step][lane][0];

            // issue bias loads for step+1
            f32x4 nA[2], nB[2];
            if (step < 17) {
#pragma unroll
                for (int qt = 0; qt < 2; qt++) {
                    int qa = q0base + qt * 16 + qloc;
                    const float* bp = bias1T + ((size_t)h * NKV1 + k0 + 32 + 4 * g) * NQ1 + qa;
#pragma unroll
                    for (int r = 0; r < 4; r++) {
                        nA[qt][r] = bp[(size_t)r * NQ1];
                        nB[qt][r] = bp[(size_t)(16 + r) * NQ1];
                    }
                }
            }

#pragma unroll
            for (int qt = 0; qt < 2; qt++) {
                f32x4 sA = __builtin_amdgcn_mfma_f32_16x16x32_bf16(kfA, qfrag[qt], cA[qt], 0, 0, 0);
                f32x4 sB = __builtin_amdgcn_mfma_f32_16x16x32_bf16(kfB, qfrag[qt], cB[qt], 0, 0, 0);
                float pa[4], pb[4];
                float ls = 0.f;
#pragma unroll
                for (int r = 0; r < 4; r++) {
                    pa[r] = exp2f(sA[r]);
                    pb[r] = exp2f(sB[r]);
                    ls += pa[r] + pb[r];
                }
                B8 pf;
                pf.u[0] = cvtpk(pa[0], pa[1]);
                pf.u[1] = cvtpk(pa[2], pa[3]);
                pf.u[2] = cvtpk(pb[0], pb[1]);
                pf.u[3] = cvtpk(pb[2], pb[3]);
                lsum[qt] += ls;
                O[qt] = __builtin_amdgcn_mfma_f32_16x16x32_bf16(vfv, pf.v, O[qt], 0, 0, 0);
            }
            if (step < 17) {
#pragma unroll
                for (int qt = 0; qt < 2; qt++) { cA[qt] = nA[qt]; cB[qt] = nB[qt]; }
            }
        }

#pragma unroll
        for (int qt = 0; qt < 2; qt++) {
            float lt = lsum[qt];
            lt += __shfl_xor(lt, 16);
            lt += __shfl_xor(lt, 32);
            float rl = 1.f / lt;
            int q = q0base + qt * 16 + qloc;
            int pix = (wi * WSZ + (q >> 4)) * WW + wj * WSZ + (q & 15);
            size_t base = (size_t)pix * 128 + h * HD + 4 * g;
#pragma unroll
            for (int r = 0; r < 4; r++)
                xcat[base + r] = O[qt][r] * rl + lnx[base + r];
        }
    } else {
        // ---------------- attn2: 576 patch q x 256 window keys ----------------
        const int bx = blockIdx.x - 288;
        const int win = bx % 144, z = bx / 144;
        const int wi = win / NWIN, wj = win % NWIN;

        {
            int n = tid;
            int pix = (wi * WSZ + (n >> 4)) * WW + wj * WSZ + (n & 15);
            const unsigned* src = qkvu + (size_t)pix * 192 + 128 + 16 * h;
            uint4 k0v = *(const uint4*)(src);
            uint4 k1v = *(const uint4*)(src + 4);
            uint4 v0v = *(const uint4*)(src + 8);
            uint4 v1v = *(const uint4*)(src + 12);
            int sn = (n >> 2) & 1;
            *(uint4*)&K_lds[n][4 * sn]       = k0v;
            *(uint4*)&K_lds[n][4 * (1 - sn)] = k1v;
            int step = n >> 5, ko = n & 31;
            int gq = (ko & 15) >> 2;
            int j = (ko & 3) | ((ko >> 4) << 2);
            unsigned vv[8] = {v0v.x, v0v.y, v0v.z, v0v.w, v1v.x, v1v.y, v1v.z, v1v.w};
            unsigned short* vt = &Vt[step][gq * 16][j];
#pragma unroll
            for (int d = 0; d < 8; d++) {
                vt[(2 * d) * 8]     = (unsigned short)(vv[d] & 0xffff);
                vt[(2 * d + 1) * 8] = (unsigned short)(vv[d] >> 16);
            }
        }
        __syncthreads();

        const int q0base = z * 192 + w * 48;
        bf16x8 qfrag[3];
        bool qin[3];
        int qpix[3];
#pragma unroll
        for (int qt = 0; qt < 3; qt++) {
            int qa = q0base + qt * 16 + qloc;
            int gr = wi * WSZ - PADK + qa / OWSZ, gc = wj * WSZ - PADK + qa % OWSZ;
            bool ib = (gr >= 0 && gr < HH && gc >= 0 && gc < WW);
            qin[qt] = ib;
            qpix[qt] = ib ? gr * WW + gc : 0;
            B8 f;
#pragma unroll
            for (int j = 0; j < 4; j++) f.u[j] = 0;
            if (ib && g < 2)
                f.v = *(const bf16x8*)(qkvu + (size_t)qpix[qt] * 192 + 32 + 8 * h + 4 * g);
            qfrag[qt] = f.v;
        }

        f32x4 O[3];
        float lsum[3];
#pragma unroll
        for (int qt = 0; qt < 3; qt++) { O[qt] = zz; lsum[qt] = 0.f; }

        f32x4 cA[3], cB[3];
#pragma unroll
        for (int qt = 0; qt < 3; qt++) {
            int qa = q0base + qt * 16 + qloc;
            const float* bp = bias2T + ((size_t)h * NQ1 + 4 * g) * NKV1 + qa;
#pragma unroll
            for (int r = 0; r < 4; r++) {
                cA[qt][r] = bp[(size_t)r * NKV1];
                cB[qt][r] = bp[(size_t)(16 + r) * NKV1];
            }
        }

        for (int step = 0; step < 8; step++) {
            const int k0 = step * 32;
            bf16x8 kfA, kfB;
            if (g < 2) {
                int gs = 4 * (g ^ sw);
                kfA = *(const bf16x8*)&K_lds[k0 + qloc][gs];
                kfB = *(const bf16x8*)&K_lds[k0 + 16 + qloc][gs];
            } else {
                B8 zf;
#pragma unroll
                for (int j = 0; j < 4; j++) zf.u[j] = 0;
                kfA = zf.v; kfB = zf.v;
            }
            bf16x8 vfv = *(const bf16x8*)&Vt[step][lane][0];

            f32x4 nA[3], nB[3];
            if (step < 7) {
#pragma unroll
                for (int qt = 0; qt < 3; qt++) {
                    int qa = q0base + qt * 16 + qloc;
                    const float* bp = bias2T + ((size_t)h * NQ1 + k0 + 32 + 4 * g) * NKV1 + qa;
#pragma unroll
                    for (int r = 0; r < 4; r++) {
                        nA[qt][r] = bp[(size_t)r * NKV1];
                        nB[qt][r] = bp[(size_t)(16 + r) * NKV1];
                    }
                }
            }

#pragma unroll
            for (int qt = 0; qt < 3; qt++) {
                f32x4 sA = __builtin_amdgcn_mfma_f32_16x16x32_bf16(kfA, qfrag[qt], cA[qt], 0, 0, 0);
                f32x4 sB = __builtin_amdgcn_mfma_f32_16x16x32_bf16(kfB, qfrag[qt], cB[qt], 0, 0, 0);
                float pa[4], pb[4];
                float ls = 0.f;
#pragma unroll
                for (int r = 0; r < 4; r++) {
                    pa[r] = exp2f(sA[r]);
                    pb[r] = exp2f(sB[r]);
                    ls += pa[r] + pb[r];
                }
                B8 pf;
                pf.u[0] = cvtpk(pa[0], pa[1]);
                pf.u[1] = cvtpk(pa[2], pa[3]);
                pf.u[2] = cvtpk(pb[0], pb[1]);
                pf.u[3] = cvtpk(pb[2], pb[3]);
                lsum[qt] += ls;
                O[qt] = __builtin_amdgcn_mfma_f32_16x16x32_bf16(vfv, pf.v, O[qt], 0, 0, 0);
            }
            if (step < 7) {
#pragma unroll
                for (int qt = 0; qt < 3; qt++) { cA[qt] = nA[qt]; cB[qt] = nB[qt]; }
            }
        }

#pragma unroll
        for (int qt = 0; qt < 3; qt++) {
            float lt = lsum[qt];
            lt += __shfl_xor(lt, 16);
            lt += __shfl_xor(lt, 32);
            float rl = 1.f / lt;
            int qa = q0base + qt * 16 + qloc;
            size_t obase = ((size_t)win * NKV1 + qa) * C2K + h * HD + 4 * g;
            size_t rbase = (size_t)qpix[qt] * 128 + C2K + h * HD + 4 * g;
#pragma unroll
            for (int r = 0; r < 4; r++)
                bb[obase + r] = O[qt][r] * rl + (qin[qt] ? lnx[rbase + r] : 0.f);
        }
    }
}

// ---------------- fold (gather form, no atomics) ----------------
__global__ void fold_kernel(const float* __restrict__ bb, float* __restrict__ folded)
{
    int idx = blockIdx.x * 256 + threadIdx.x;
    if (idx >= 200 * 200 * 64) return;
    int c = idx & 63;
    int j = (idx >> 6) % 200;
    int i = idx / (64 * 200);
    int ilo = (i > 23) ? ((i - 8) >> 4) : 0;
    int ihi = min(11, i >> 4);
    int jlo = (j > 23) ? ((j - 8) >> 4) : 0;
    int jhi = min(11, j >> 4);
    float s = 0.f;
    for (int wi = ilo; wi <= ihi; wi++)
        for (int wj = jlo; wj <= jhi; wj++) {
            int p = (i - wi * 16) * OWSZ + (j - wj * 16);
            s += bb[((size_t)(wi * NWIN + wj) * NKV1 + p) * C2K + c];
        }
    folded[idx] = s;
}

// ---------------- bicubic resize 200->192 ----------------
__device__ __forceinline__ float cubicw(float x)
{
    float ax = fabsf(x);
    const float A = -0.75f;
    if (ax <= 1.f) return ((A + 2.f) * ax - (A + 3.f)) * ax * ax + 1.f;
    if (ax < 2.f)  return A * (ax * (ax * (ax - 5.f) + 8.f) - 4.f);
    return 0.f;
}

__global__ void resize_kernel(const float* __restrict__ folded, float* __restrict__ xcat)
{
    int idx = blockIdx.x * 256 + threadIdx.x;
    if (idx >= HH * WW * C2K) return;
    int c = idx & 63;
    int p = (idx >> 6) % WW;
    int o = idx / (C2K * WW);
    const float ratio = 200.f / 192.f;
    float sr = (o + 0.5f) * ratio - 0.5f;
    float sc = (p + 0.5f) * ratio - 0.5f;
    int fr = (int)floorf(sr), fcc = (int)floorf(sc);
    float wc[4]; int ic[4];
#pragma unroll
    for (int u = 0; u < 4; u++) {
        int jj = fcc - 1 + u;
        wc[u] = cubicw(sc - (float)jj);
        ic[u] = min(max(jj, 0), 199);
    }
    float acc = 0.f;
#pragma unroll
    for (int t = 0; t < 4; t++) {
        int ii = fr - 1 + t;
        float wr = cubicw(sr - (float)ii);
        int ir = min(max(ii, 0), 199);
        const float* rowp = folded + ((size_t)ir * 200) * 64 + c;
        float rs = 0.f;
#pragma unroll
        for (int u = 0; u < 4; u++) rs += wc[u] * rowp[(size_t)ic[u] * 64];
        acc += wr * rs;
    }
    xcat[(size_t)(o * WW + p) * 128 + C2K + c] = acc;
}

// ---------------- proj GEMM + residual + fused LN2 -> x_buf(f32) and y(bf16) ----------------
__launch_bounds__(256)
__global__ void proj_ln2(const float* __restrict__ A1,
                         const bf16* __restrict__ WT,
                         const float* __restrict__ bias,
                         const float* __restrict__ R,
                         const float* __restrict__ ln2w, const float* __restrict__ ln2b,
                         float* __restrict__ xbuf, unsigned* __restrict__ ybf)
{
    __shared__ float psum[16][16];
    __shared__ float psq[16][16];
    __shared__ float mu_s[16], inv_s[16];

    const int tid = threadIdx.x;
    const int lane = tid & 63, w = tid >> 6;
    const int g = lane >> 4, nl = lane & 15;

    bf16x8 wf[2][4];
#pragma unroll
    for (int t = 0; t < 2; t++) {
        const bf16* wp = WT + (size_t)((w * 2 + t) * 16 + nl) * 128;
#pragma unroll
        for (int ks = 0; ks < 4; ks++)
            wf[t][ks] = *(const bf16x8*)(wp + ks * 32 + 8 * g);
    }

    const int row = (blockIdx.x * 4 + blockIdx.y) * 16 + nl;
    bf16x8 xf[4];
    const float* ap = A1 + (size_t)row * 128 + 8 * g;
#pragma unroll
    for (int ks = 0; ks < 4; ks++) {
        float4 v0 = *(const float4*)(ap + ks * 32);
        float4 v1 = *(const float4*)(ap + ks * 32 + 4);
        B8 f;
        f.u[0] = cvtpk(v0.x, v0.y);
        f.u[1] = cvtpk(v0.z, v0.w);
        f.u[2] = cvtpk(v1.x, v1.y);
        f.u[3] = cvtpk(v1.z, v1.w);
        xf[ks] = f.v;
    }

    const f32x4 zz = {0.f, 0.f, 0.f, 0.f};
    f32x4 acc[2];
    acc[0] = zz; acc[1] = zz;
#pragma unroll
    for (int ks = 0; ks < 4; ks++) {
        acc[0] = __builtin_amdgcn_mfma_f32_16x16x32_bf16(wf[0][ks], xf[ks], acc[0], 0, 0, 0);
        acc[1] = __builtin_amdgcn_mfma_f32_16x16x32_bf16(wf[1][ks], xf[ks], acc[1], 0, 0, 0);
    }

    float o[2][4];
    float s = 0.f, sq = 0.f;
#pragma unroll
    for (int t = 0; t < 2; t++) {
        int n0t = (w * 2 + t) * 16 + 4 * g;
        float4 bv = *(const float4*)(bias + n0t);
        float4 rv = *(const float4*)(R + (size_t)row * 128 + n0t);
        o[t][0] = acc[t][0] + bv.x + rv.x;
        o[t][1] = acc[t][1] + bv.y + rv.y;
        o[t][2] = acc[t][2] + bv.z + rv.z;
        o[t][3] = acc[t][3] + bv.w + rv.w;
#pragma unroll
        for (int r = 0; r < 4; r++) { s += o[t][r]; sq += o[t][r] * o[t][r]; }
    }
    psum[nl][w * 4 + g] = s;
    psq[nl][w * 4 + g] = sq;
    __syncthreads();
    if (tid < 16) {
        float ts = 0.f, tq = 0.f;
#pragma unroll
        for (int i = 0; i < 16; i++) { ts += psum[tid][i]; tq += psq[tid][i]; }
        float mu = ts * 0.0078125f;
        float var = fmaxf(tq * 0.0078125f - mu * mu, 0.f);
        mu_s[tid] = mu;
        inv_s[tid] = 1.0f / sqrtf(var + 1e-5f);
    }
    __syncthreads();

    float mu = mu_s[nl], inv = inv_s[nl];
#pragma unroll
    for (int t = 0; t < 2; t++) {
        int n0t = (w * 2 + t) * 16 + 4 * g;
        *(float4*)(xbuf + (size_t)row * 128 + n0t) = make_float4(o[t][0], o[t][1], o[t][2], o[t][3]);
        float4 gw = *(const float4*)(ln2w + n0t);
        float4 gb = *(const float4*)(ln2b + n0t);
        float y0 = (o[t][0] - mu) * inv * gw.x + gb.x;
        float y1 = (o[t][1] - mu) * inv * gw.y + gb.y;
        float y2 = (o[t][2] - mu) * inv * gw.z + gb.z;
        float y3 = (o[t][3] - mu) * inv * gw.w + gb.w;
        uint2 yo;
        yo.x = cvtpk(y0, y1);
        yo.y = cvtpk(y2, y3);
        *(uint2*)(ybf + (size_t)row * 64 + (n0t >> 1)) = yo;
    }
}

// ---------------- fc1 GEMM (A bf16) + fused sgn-LN -> x1b (bf16) | x2b (LN'd bf16) ----------------
__launch_bounds__(256)
__global__ void fc1_sgn(const unsigned* __restrict__ ybf,
                        const bf16* __restrict__ WT,
                        const float* __restrict__ bias,
                        const float* __restrict__ sgnw, const float* __restrict__ sgnb,
                        unsigned* __restrict__ x1b, unsigned* __restrict__ x2b)
{
    __shared__ float psum[16][8];
    __shared__ float psq[16][8];
    __shared__ float mu_s[16], inv_s[16];

    const int tid = threadIdx.x;
    const int lane = tid & 63, w = tid >> 6;
    const int g = lane >> 4, nl = lane & 15;

    bf16x8 wf[4][4];
#pragma unroll
    for (int t = 0; t < 4; t++) {
        const bf16* wp = WT + (size_t)((w * 4 + t) * 16 + nl) * 128;
#pragma unroll
        for (int ks = 0; ks < 4; ks++)
            wf[t][ks] = *(const bf16x8*)(wp + ks * 32 + 8 * g);
    }

    const int row = (blockIdx.x * 4 + blockIdx.y) * 16 + nl;
    bf16x8 xf[4];
    const unsigned* ap = ybf + (size_t)row * 64 + 4 * g;
#pragma unroll
    for (int ks = 0; ks < 4; ks++)
        xf[ks] = *(const bf16x8*)(ap + ks * 16);

    const f32x4 zz = {0.f, 0.f, 0.f, 0.f};
    f32x4 acc[4];
#pragma unroll
    for (int t = 0; t < 4; t++) acc[t] = zz;
#pragma unroll
    for (int ks = 0; ks < 4; ks++)
#pragma unroll
        for (int t = 0; t < 4; t++)
            acc[t] = __builtin_amdgcn_mfma_f32_16x16x32_bf16(wf[t][ks], xf[ks], acc[t], 0, 0, 0);

    float o[4][4];
    float s = 0.f, sq = 0.f;
#pragma unroll
    for (int t = 0; t < 4; t++) {
        int n0t = (w * 4 + t) * 16 + 4 * g;
        float4 bv = *(const float4*)(bias + n0t);
        o[t][0] = acc[t][0] + bv.x;
        o[t][1] = acc[t][1] + bv.y;
        o[t][2] = acc[t][2] + bv.z;
        o[t][3] = acc[t][3] + bv.w;
    }
    if (w >= 2) {
#pragma unroll
        for (int t = 0; t < 4; t++)
#pragma unroll
            for (int r = 0; r < 4; r++) { s += o[t][r]; sq += o[t][r] * o[t][r]; }
        psum[nl][(w - 2) * 4 + g] = s;
        psq[nl][(w - 2) * 4 + g] = sq;
    }
    __syncthreads();
    if (tid < 16) {
        float ts = 0.f, tq = 0.f;
#pragma unroll
        for (int i = 0; i < 8; i++) { ts += psum[tid][i]; tq += psq[tid][i]; }
        float mu = ts * 0.0078125f;
        float var = fmaxf(tq * 0.0078125f - mu * mu, 0.f);
        mu_s[tid] = mu;
        inv_s[tid] = 1.0f / sqrtf(var + 1e-5f);
    }
    __syncthreads();

    if (w < 2) {
#pragma unroll
        for (int t = 0; t < 4; t++) {
            int n0t = (w * 4 + t) * 16 + 4 * g;   // 0..127
            uint2 xo;
            xo.x = cvtpk(o[t][0], o[t][1]);
            xo.y = cvtpk(o[t][2], o[t][3]);
            *(uint2*)(x1b + (size_t)row * 64 + (n0t >> 1)) = xo;
        }
    } else {
        float mu = mu_s[nl], inv = inv_s[nl];
#pragma unroll
        for (int t = 0; t < 4; t++) {
            int n0t = (w * 4 + t) * 16 + 4 * g;
            int m0t = n0t - 128;                  // 0..127
            float4 gw = *(const float4*)(sgnw + m0t);
            float4 gb = *(const float4*)(sgnb + m0t);
            float y0 = (o[t][0] - mu) * inv * gw.x + gb.x;
            float y1 = (o[t][1] - mu) * inv * gw.y + gb.y;
            float y2 = (o[t][2] - mu) * inv * gw.z + gb.z;
            float y3 = (o[t][3] - mu) * inv * gw.w + gb.w;
            uint2 xo;
            xo.x = cvtpk(y0, y1);
            xo.y = cvtpk(y2, y3);
            *(uint2*)(x2b + (size_t)row * 64 + (m0t >> 1)) = xo;
        }
    }
}

// ---------------- depthwise 3x3 conv on bf16 x2, fused x1 multiply -> ab (bf16) ----------------
// scalar proven form
__global__ void dwconv_kernel(const unsigned short* __restrict__ x2b,
                              const unsigned short* __restrict__ x1b,
                              const float* __restrict__ conv_w,
                              const float* __restrict__ conv_b,
                              unsigned short* __restrict__ ab)
{
    int idx = blockIdx.x * 256 + threadIdx.x;
    if (idx >= NTOK * 128) return;
    int ch = idx & 127, t = idx >> 7;
    int i = t / WW, j = t % WW;
    float acc = conv_b[ch];
#pragma unroll
    for (int a = 0; a < 3; a++) {
        int ii = i + a - 1;
        if (ii < 0 || ii >= HH) continue;
#pragma unroll
        for (int b = 0; b < 3; b++) {
            int jj = j + b - 1;
            if (jj < 0 || jj >= WW) continue;
            acc += conv_w[ch * 9 + a * 3 + b] * bfu2f(x2b[(size_t)(ii * WW + jj) * 128 + ch]);
        }
    }
    float prod = bfu2f(x1b[(size_t)t * 128 + ch]) * acc;
    unsigned u = __float_as_uint(prod);
    ab[(size_t)t * 128 + ch] = (unsigned short)((u + 0x7FFFu + ((u >> 16) & 1u)) >> 16);
}

// ---------------- fc2 GEMM (A bf16 direct) + bias + residual -> out f32, N=128 ----------------
__launch_bounds__(256)
__global__ void gemm_bfA(const unsigned* __restrict__ Au,
                         const bf16* __restrict__ WT,
                         const float* __restrict__ bias,
                         const float* __restrict__ R,
                         float* __restrict__ C)
{
    const int tid = threadIdx.x;
    const int lane = tid & 63, w = tid >> 6;
    const int g = lane >> 4, nl = lane & 15;

    bf16x8 wf[2][4];
#pragma unroll
    for (int t = 0; t < 2; t++) {
        const bf16* wp = WT + (size_t)((w * 2 + t) * 16 + nl) * 128;
#pragma unroll
        for (int ks = 0; ks < 4; ks++)
            wf[t][ks] = *(const bf16x8*)(wp + ks * 32 + 8 * g);
    }

    const int row = (blockIdx.x * 4 + blockIdx.y) * 16 + nl;
    bf16x8 xf[4];
    const unsigned* ap = Au + (size_t)row * 64 + 4 * g;
#pragma unroll
    for (int ks = 0; ks < 4; ks++)
        xf[ks] = *(const bf16x8*)(ap + ks * 16);

    const f32x4 zz = {0.f, 0.f, 0.f, 0.f};
    f32x4 acc[2];
    acc[0] = zz; acc[1] = zz;
#pragma unroll
    for (int ks = 0; ks < 4; ks++) {
        acc[0] = __builtin_amdgcn_mfma_f32_16x16x32_bf16(wf[0][ks], xf[ks], acc[0], 0, 0, 0);
        acc[1] = __builtin_amdgcn_mfma_f32_16x16x32_bf16(wf[1][ks], xf[ks], acc[1], 0, 0, 0);
    }

#pragma unroll
    for (int t = 0; t < 2; t++) {
        const int n0t = (w * 2 + t) * 16 + 4 * g;
        float4 bv = *(const float4*)(bias + n0t);
        float4 rv = *(const float4*)(R + (size_t)row * 128 + n0t);
        float4 o;
        o.x = acc[t][0] + bv.x + rv.x;
        o.y = acc[t][1] + bv.y + rv.y;
        o.z = acc[t][2] + bv.z + rv.z;
        o.w = acc[t][3] + bv.w + rv.w;
        *(float4*)(C + (size_t)row * 128 + n0t) = o;
    }
}

extern "C" void kernel_launch(void* const* d_in, const int* in_sizes, int n_in,
                              void* d_out, int out_size, void* d_ws, size_t ws_size,
                              hipStream_t stream)
{
    (void)in_sizes; (void)n_in; (void)out_size; (void)ws_size;
    const float* x_tkn  = (const float*)d_in[0];
    const float* ln1_w  = (const float*)d_in[1];
    const float* ln1_b  = (const float*)d_in[2];
    const float* q1_w   = (const float*)d_in[3];
    const float* kv1_w  = (const float*)d_in[4];
    const float* rpb1   = (const float*)d_in[5];
    const float* q2_w   = (const float*)d_in[6];
    const float* kv2_w  = (const float*)d_in[7];
    const float* rpb2   = (const float*)d_in[8];
    const float* proj_w = (const float*)d_in[9];
    const float* proj_b = (const float*)d_in[10];
    const float* ln2_w  = (const float*)d_in[11];
    const float* ln2_b  = (const float*)d_in[12];
    const float* fc1_w  = (const float*)d_in[13];
    const float* fc1_b  = (const float*)d_in[14];
    const float* sgn_w  = (const float*)d_in[15];
    const float* sgn_b  = (const float*)d_in[16];
    const float* conv_w = (const float*)d_in[17];
    const float* conv_b = (const float*)d_in[18];
    const float* fc2_w  = (const float*)d_in[19];
    const float* fc2_b  = (const float*)d_in[20];
    const int*   rpi    = (const int*)d_in[21];

    float* ws = (float*)d_ws;
    // layout (float units); ordered-alias verified (same as rounds 12-17):
    float* lnx    = ws;                      // 0 .. 4,718,592    (LN1 out; later x_buf)
    float* xcat   = ws + 4718592;            // .. 9,437,184      (x_cat)
    float* bbuf   = ws + 9437184;            // .. 14,745,600     (bb; later ybf)
    bf16*  projT  = (bf16*)(ws + 14155776);  // bb tail, written AFTER fold
    bf16*  fc1T   = (bf16*)(ws + 14163968);
    bf16*  fc2T   = (bf16*)(ws + 14180352);
    float* bias1T = ws + 14745600;           // .. 15,335,424 (dead after attn)
    float* bias2T = ws + 17104896;           // .. 17,694,720 (dead after attn)
    float* qkv    = ws + 17694720;           // .. 24,772,608 (192 uints/row; dead after attn)
    bf16*  wcombT = (bf16*)(ws + 24772608);  // .. 24,797,184 (dead after qkv gemm)
    float* foldp  = ws + 17694720;           // aliases qkv (dead after resize)
    unsigned* ybf = (unsigned*)bbuf;         // bb dead after fold
    unsigned* x1b = (unsigned*)(ws + 14745600);  // .. 17,104,896
    unsigned* x2b = (unsigned*)(ws + 17104896);  // .. 19,464,192
    unsigned* ab  = (unsigned*)(ws + 19464192);  // .. 21,823,488
    float* out    = (float*)d_out;

    // 1. weight + bias prep
    wcombT_kernel<<<(384 * 128) / 256, 256, 0, stream>>>(q1_w, kv1_w, q2_w, kv2_w, wcombT);
    bias1_kernel<<<(H2K * NKV1 * NQ1) / 256, 256, 0, stream>>>(rpb1, rpi, bias1T);
    bias2_kernel<<<(H2K * NQ1 * NKV1) / 256, 256, 0, stream>>>(rpb2, rpi, bias2T);
    // 2. qkv = LN1(x_tkn) @ Wcomb (N=384) -> bf16; also writes lnx f32
    gemm_qkv<<<dim3(NTOK / 64, 4), 256, 0, stream>>>(x_tkn, ln1_w, ln1_b, wcombT,
                                                     (unsigned*)qkv, lnx);
    // 3. fused attention (K swizzled 32B rows -> 4 blocks/CU; V transposed; bias prefetched C)
    attn_fused<<<dim3(720, 4), 256, 0, stream>>>((const unsigned*)qkv, lnx,
                                                 bias1T, bias2T, xcat, bbuf);
    // 4. fold bb -> folded (200x200x64)
    fold_kernel<<<(200 * 200 * 64) / 256, 256, 0, stream>>>(bbuf, foldp);
    // 4b. transpose fc weights into bb tail (bb dead)
    wtrans_kernel<<<(128 * 128) / 256, 256, 0, stream>>>(proj_w, 128, projT);
    wtrans_kernel<<<(256 * 128) / 256, 256, 0, stream>>>(fc1_w, 256, fc1T);
    wtrans_kernel<<<(128 * 128) / 256, 256, 0, stream>>>(fc2_w, 128, fc2T);
    // 5. bicubic resize -> xcat[:, 64:128]
    resize_kernel<<<(HH * WW * C2K) / 256, 256, 0, stream>>>(foldp, xcat);
    // 6. proj + residual + fused LN2: x_buf(lnx, f32) and y(ybf, bf16)
    proj_ln2<<<dim3(NTOK / 64, 4), 256, 0, stream>>>(xcat, projT, proj_b, x_tkn,
                                                     ln2_w, ln2_b, lnx, ybf);
    // 7. fc1 + fused sgn-LN -> x1b, x2b (compact bf16)
    fc1_sgn<<<dim3(NTOK / 64, 4), 256, 0, stream>>>(ybf, fc1T, fc1_b, sgn_w, sgn_b, x1b, x2b);
    // 8. depthwise conv + x1 multiply -> ab (bf16), scalar proven form
    dwconv_kernel<<<(NTOK * 128) / 256, 256, 0, stream>>>((const unsigned short*)x2b,
                                                          (const unsigned short*)x1b,
                                                          conv_w, conv_b,
                                                          (unsigned short*)ab);
    // 9. fc2: out = ab @ fc2_w + fc2_b + x_buf
    gemm_bfA<<<dim3(NTOK / 64, 4), 256, 0, stream>>>(ab, fc2T, fc2_b, lnx, out);
}